// Round 11
// baseline (984.245 us; speedup 1.0000x reference)
//
#include <hip/hip_runtime.h>
#include <hip/hip_bf16.h>

typedef __hip_bfloat16 bf16;
typedef unsigned short ushort_t;
typedef __attribute__((ext_vector_type(8))) short bf16x8;
typedef __attribute__((ext_vector_type(16))) float f32x16;

__device__ __forceinline__ float us2f(unsigned short u) {
    unsigned int x = ((unsigned int)u) << 16;
    return __uint_as_float(x);
}

// async global->LDS, 16 B per lane. LDS dest = wave-uniform base + lane*16.
__device__ __forceinline__ void gl_lds16(const ushort_t* g, ushort_t* l) {
    __builtin_amdgcn_global_load_lds(
        (const __attribute__((address_space(1))) void*)g,
        (__attribute__((address_space(3))) void*)l, 16, 0, 0);
}

// ---------------------------------------------------------------------------
// Vectorized transposed tile store through per-wave LDS (stride 33 floats:
// 33 % 32 == 1 -> <=2-way bank aliasing, free). 16 contiguous elements per
// lane (2x dwordx4 bf16 / 4x dwordx4 f32). Barrier-free (same-wave DS order).
// LDS region is OVERLAID on staging memory (R10 lesson: additive tlds cost
// 17 KB -> occupancy 45->24% -> regression).
// ---------------------------------------------------------------------------
template<bool RELU, bool OUT_BF16, bool HAS_RESID>
__device__ __forceinline__ void epi_store_tile(
    float* __restrict__ tl, const f32x16& acc, int lane,
    int mbase, int nbase, const float* __restrict__ bias,
    const float* __restrict__ resid, void* __restrict__ outv, int M, int N)
{
    const int l32 = lane & 31, hi = lane >> 5;
    #pragma unroll
    for (int r = 0; r < 16; ++r) {
        const int row = (r & 3) + ((r >> 2) << 3) + hi * 4;
        tl[row * 33 + l32] = acc[r];
    }
    const int rr = lane >> 1;
    const int cc = (lane & 1) * 16;
    const int m  = mbase + rr;
    const int nb = nbase + cc;
    if (m >= M || nb >= N) return;

    if (OUT_BF16) {
        bf16* op = (bf16*)outv + (size_t)m * N + nb;
        #pragma unroll
        for (int gv = 0; gv < 2; ++gv) {
            unsigned pk[4];
            #pragma unroll
            for (int q = 0; q < 2; ++q) {
                const int c = cc + gv * 8 + q * 4;
                const float4 v  = *reinterpret_cast<const float4*>(&tl[rr * 33 + c]);
                const float4 b4 = *reinterpret_cast<const float4*>(&bias[nbase + c]);
                float o0 = v.x + b4.x, o1 = v.y + b4.y;
                float o2 = v.z + b4.z, o3 = v.w + b4.w;
                if (HAS_RESID) {
                    const float4 r4 = *reinterpret_cast<const float4*>(
                        &resid[(size_t)m * N + nbase + c]);
                    o0 += r4.x; o1 += r4.y; o2 += r4.z; o3 += r4.w;
                }
                if (RELU) {
                    o0 = fmaxf(o0, 0.f); o1 = fmaxf(o1, 0.f);
                    o2 = fmaxf(o2, 0.f); o3 = fmaxf(o3, 0.f);
                }
                pk[q * 2 + 0] =
                    (unsigned)((__hip_bfloat16_raw)__float2bfloat16(o0)).x |
                    ((unsigned)((__hip_bfloat16_raw)__float2bfloat16(o1)).x << 16);
                pk[q * 2 + 1] =
                    (unsigned)((__hip_bfloat16_raw)__float2bfloat16(o2)).x |
                    ((unsigned)((__hip_bfloat16_raw)__float2bfloat16(o3)).x << 16);
            }
            int4 w4; w4.x = pk[0]; w4.y = pk[1]; w4.z = pk[2]; w4.w = pk[3];
            *reinterpret_cast<int4*>(op + gv * 8) = w4;
        }
    } else {
        float* op = (float*)outv + (size_t)m * N + nb;
        #pragma unroll
        for (int q = 0; q < 4; ++q) {
            const int c = cc + q * 4;
            const float4 v  = *reinterpret_cast<const float4*>(&tl[rr * 33 + c]);
            const float4 b4 = *reinterpret_cast<const float4*>(&bias[nbase + c]);
            float4 o;
            o.x = v.x + b4.x; o.y = v.y + b4.y;
            o.z = v.z + b4.z; o.w = v.w + b4.w;
            if (HAS_RESID) {
                const float4 r4 = *reinterpret_cast<const float4*>(
                    &resid[(size_t)m * N + nbase + c]);
                o.x += r4.x; o.y += r4.y; o.z += r4.z; o.w += r4.w;
            }
            if (RELU) {
                o.x = fmaxf(o.x, 0.f); o.y = fmaxf(o.y, 0.f);
                o.z = fmaxf(o.z, 0.f); o.w = fmaxf(o.w, 0.f);
            }
            *reinterpret_cast<float4*>(op + q * 4) = o;
        }
    }
}

// ---------------------------------------------------------------------------
// Fused input cast: src_b = bf16(src), q_b = bf16(src + pos)
// ---------------------------------------------------------------------------
__global__ __launch_bounds__(256) void cast2_kernel(
    const float* __restrict__ src, const float* __restrict__ pos,
    bf16* __restrict__ src_b, bf16* __restrict__ q_b, int n)
{
    int i = blockIdx.x * 256 + threadIdx.x;
    if (i < n) {
        float s = src[i];
        src_b[i] = __float2bfloat16(s);
        q_b[i]   = __float2bfloat16(s + pos[i]);
    }
}

// ---------------------------------------------------------------------------
// Fused weight prep: all transpose-casts + bias concat in ONE launch.
// ---------------------------------------------------------------------------
__global__ __launch_bounds__(256) void prep_kernel(
    const float* __restrict__ wv, const float* __restrict__ wo,
    const float* __restrict__ wa, const float* __restrict__ wout,
    const float* __restrict__ w1, const float* __restrict__ w2,
    const float* __restrict__ bo, const float* __restrict__ ba,
    bf16* __restrict__ wvt, bf16* __restrict__ wcat, bf16* __restrict__ woutt,
    bf16* __restrict__ w1t, bf16* __restrict__ w2t, float* __restrict__ bcat)
{
    __shared__ float tile[32][33];
    const int b = blockIdx.x;
    const float* W; bf16* Wt; int K, N, tb;
    if (b < 64)        { W = wv;   Wt = wvt;            K = 256;  N = 256;  tb = b; }
    else if (b < 144)  { W = wo;   Wt = wcat;           K = 256;  N = 320;  tb = b - 64; }
    else if (b < 184)  { W = wa;   Wt = wcat + 320*256; K = 256;  N = 160;  tb = b - 144; }
    else if (b < 248)  { W = wout; Wt = woutt;          K = 256;  N = 256;  tb = b - 184; }
    else if (b < 760)  { W = w1;   Wt = w1t;            K = 256;  N = 2048; tb = b - 248; }
    else if (b < 1272) { W = w2;   Wt = w2t;            K = 2048; N = 256;  tb = b - 760; }
    else {
        int i = (b - 1272) * 256 + threadIdx.x;
        if (i < 320) bcat[i] = bo[i];
        else if (i < 480) bcat[i] = ba[i - 320];
        return;
    }
    const int ntn = N >> 5;
    const int nb = (tb % ntn) * 32, kb = (tb / ntn) * 32;
    const int tx = threadIdx.x & 31, ty = threadIdx.x >> 5;  // 32 x 8
    #pragma unroll
    for (int i = 0; i < 32; i += 8) {
        int k = kb + ty + i, n = nb + tx;
        tile[ty + i][tx] = (k < K && n < N) ? W[(size_t)k * N + n] : 0.f;
    }
    __syncthreads();
    #pragma unroll
    for (int i = 0; i < 32; i += 8) {
        int n = nb + ty + i, k = kb + tx;
        if (n < N && k < K)
            Wt[(size_t)n * K + k] = __float2bfloat16(tile[tx][ty + i]);
    }
}

// ---------------------------------------------------------------------------
// MFMA bf16 GEMM (128x128 tile): for large-N GEMMs (og N=480, FFN1 N=2048).
// LDS: staging (16 KB) and epilogue (16.5 KB) OVERLAID -> 16.9 KB total.
// ---------------------------------------------------------------------------
template<bool RELU, bool OUT_BF16, bool HAS_RESID>
__global__ __launch_bounds__(256, 4) void gemm_mfma(
    const ushort_t* __restrict__ A,    // [M][K] bf16
    const ushort_t* __restrict__ Bt,   // [N][K] bf16
    const float* __restrict__ bias,    // [N] f32
    const float* __restrict__ resid,   // [M][N] f32
    void* __restrict__ outv, int M, int N, int K)
{
    __shared__ union SM {
        struct { ushort_t A[128 * 32]; ushort_t B[128 * 32]; } st;
        float epi[4][32 * 33];
    } sm;
    const int tid = threadIdx.x;
    const int lane = tid & 63;
    const int wave = tid >> 6;
    const int l32 = lane & 31;
    const int hi  = lane >> 5;
    const int wm = wave >> 1, wn = wave & 1;
    const int m0 = blockIdx.y * 128;
    const int n0 = blockIdx.x * 128;

    const int srow = lane >> 2;
    const int sch  = (lane & 3) * 8;

    const ushort_t* aP[2]; const ushort_t* bP[2];
    ushort_t* aL[2]; ushort_t* bL[2];
    #pragma unroll
    for (int i = 0; i < 2; ++i) {
        const int rbase = wave * 32 + i * 16;
        int mA = m0 + rbase + srow; if (mA > M - 1) mA = M - 1;
        int nB = n0 + rbase + srow; if (nB > N - 1) nB = N - 1;
        aP[i] = A  + (size_t)mA * K + sch;
        bP[i] = Bt + (size_t)nB * K + sch;
        aL[i] = &sm.st.A[rbase * 32];
        bL[i] = &sm.st.B[rbase * 32];
    }

    f32x16 acc[2][2] = {};

    for (int k0 = 0; k0 < K; k0 += 32) {
        #pragma unroll
        for (int i = 0; i < 2; ++i) {
            gl_lds16(aP[i], aL[i]);
            gl_lds16(bP[i], bL[i]);
            aP[i] += 32; bP[i] += 32;
        }
        __syncthreads();

        #pragma unroll
        for (int kw = 0; kw < 2; ++kw) {
            bf16x8 af[2], bfr[2];
            #pragma unroll
            for (int i = 0; i < 2; ++i) {
                const int rowA = wm * 64 + i * 32 + l32;
                af[i] = *reinterpret_cast<const bf16x8*>(
                    &sm.st.A[rowA * 32 + kw * 16 + hi * 8]);
                const int rowB = wn * 64 + i * 32 + l32;
                bfr[i] = *reinterpret_cast<const bf16x8*>(
                    &sm.st.B[rowB * 32 + kw * 16 + hi * 8]);
            }
            #pragma unroll
            for (int i = 0; i < 2; ++i)
                #pragma unroll
                for (int j = 0; j < 2; ++j)
                    acc[i][j] = __builtin_amdgcn_mfma_f32_32x32x16_bf16(
                        af[i], bfr[j], acc[i][j], 0, 0, 0);
        }
        __syncthreads();
    }
    // staging LDS is dead past here (final barrier above) -> epi overlays it.

    float* tl = &sm.epi[wave][0];
    #pragma unroll
    for (int i = 0; i < 2; ++i)
        #pragma unroll
        for (int j = 0; j < 2; ++j)
            epi_store_tile<RELU, OUT_BF16, HAS_RESID>(
                tl, acc[i][j], lane,
                m0 + wm * 64 + i * 32, n0 + wn * 64 + j * 32,
                bias, resid, outv, M, N);
}

// ---------------------------------------------------------------------------
// MFMA bf16 GEMM (64x128 tile, M-split): for N=256 GEMMs (value, wout, FFN2).
// Parallelism from M -> no A-fetch inflation (R8 lesson). LDS overlaid.
// ---------------------------------------------------------------------------
template<bool RELU, bool OUT_BF16, bool HAS_RESID>
__global__ __launch_bounds__(256, 4) void gemm_mfma_s(
    const ushort_t* __restrict__ A,    // [M][K] bf16
    const ushort_t* __restrict__ Bt,   // [N][K] bf16
    const float* __restrict__ bias,    // [N] f32
    const float* __restrict__ resid,   // [M][N] f32
    void* __restrict__ outv, int M, int N, int K)
{
    __shared__ union SM {
        struct { ushort_t A[64 * 32]; ushort_t B[128 * 32]; } st;
        float epi[4][32 * 33];
    } sm;
    const int tid = threadIdx.x;
    const int lane = tid & 63;
    const int wave = tid >> 6;
    const int l32 = lane & 31;
    const int hi  = lane >> 5;
    const int wm = wave >> 1;
    const int wn = wave & 1;
    const int m0 = blockIdx.y * 64;
    const int n0 = blockIdx.x * 128;

    const int srow = lane >> 2;
    const int sch  = (lane & 3) * 8;

    int mA = m0 + wave * 16 + srow; if (mA > M - 1) mA = M - 1;
    const ushort_t* aP = A + (size_t)mA * K + sch;
    ushort_t* aL = &sm.st.A[(wave * 16) * 32];
    const ushort_t* bP[2]; ushort_t* bL[2];
    #pragma unroll
    for (int i = 0; i < 2; ++i) {
        const int rbase = wave * 32 + i * 16;
        int nB = n0 + rbase + srow; if (nB > N - 1) nB = N - 1;
        bP[i] = Bt + (size_t)nB * K + sch;
        bL[i] = &sm.st.B[rbase * 32];
    }

    f32x16 acc[2] = {};

    for (int k0 = 0; k0 < K; k0 += 32) {
        gl_lds16(aP, aL);       aP    += 32;
        gl_lds16(bP[0], bL[0]); bP[0] += 32;
        gl_lds16(bP[1], bL[1]); bP[1] += 32;
        __syncthreads();

        #pragma unroll
        for (int kw = 0; kw < 2; ++kw) {
            const bf16x8 af = *reinterpret_cast<const bf16x8*>(
                &sm.st.A[(wm * 32 + l32) * 32 + kw * 16 + hi * 8]);
            bf16x8 bfr[2];
            #pragma unroll
            for (int j = 0; j < 2; ++j) {
                const int rowB = wn * 64 + j * 32 + l32;
                bfr[j] = *reinterpret_cast<const bf16x8*>(
                    &sm.st.B[rowB * 32 + kw * 16 + hi * 8]);
            }
            #pragma unroll
            for (int j = 0; j < 2; ++j)
                acc[j] = __builtin_amdgcn_mfma_f32_32x32x16_bf16(
                    af, bfr[j], acc[j], 0, 0, 0);
        }
        __syncthreads();
    }
    // staging LDS dead past here -> epi overlays it.

    float* tl = &sm.epi[wave][0];
    #pragma unroll
    for (int j = 0; j < 2; ++j)
        epi_store_tile<RELU, OUT_BF16, HAS_RESID>(
            tl, acc[j], lane,
            m0 + wm * 32, n0 + wn * 64 + j * 32,
            bias, resid, outv, M, N);
}

// ---------------------------------------------------------------------------
// MS-deformable attention v3: phase-A tuple setup + phase-B pure gather-FMA.
// ---------------------------------------------------------------------------
__global__ __launch_bounds__(256) void msda_kernel_v3(
    const float* __restrict__ og,        // [M,480]: offs 0..319, logits 320..479
    const float* __restrict__ refp,      // [M,10]
    const ushort_t* __restrict__ value,  // [M,256] bf16 = (B,L,H,32)
    bf16* __restrict__ out,              // [M,256] bf16
    int M, int L)
{
    const int tid = threadIdx.x;
    const int qbase = blockIdx.x * 8;

    __shared__ float  s_attn[8][160];
    __shared__ int2   s_off[1280];
    __shared__ float4 s_w[1280];
    __shared__ int    s_Wl[5], s_St[5];

    if (tid < 5) {
        const int HW[5] = {100, 50, 25, 13, 7};
        const int st[5] = {0, 10000, 12500, 13125, 13294};
        s_Wl[tid] = HW[tid];
        s_St[tid] = st[tid];
    }

    for (int i = tid; i < 1280; i += 256) {
        int q = i / 160, j = i - q * 160;
        int qq = qbase + q;
        s_attn[q][j] = (qq < M) ? og[(size_t)qq * 480 + 320 + j] : 0.f;
    }
    __syncthreads();

    if (tid < 64) {
        float* a = &s_attn[tid >> 3][(tid & 7) * 20];
        float mx = -1e30f;
        #pragma unroll
        for (int i = 0; i < 20; ++i) mx = fmaxf(mx, a[i]);
        float ssum = 0.f;
        #pragma unroll
        for (int i = 0; i < 20; ++i) {
            float e = __expf(a[i] - mx);
            a[i] = e;
            ssum += e;
        }
        float inv = 1.f / ssum;
        #pragma unroll
        for (int i = 0; i < 20; ++i) a[i] *= inv;
    }
    __syncthreads();

    #pragma unroll
    for (int it = 0; it < 5; ++it) {
        const int t = tid + it * 256;
        const int q  = t / 160;
        const int r  = t - q * 160;
        const int l  = (r - (r / 20) * 20) >> 2;
        const int qq = qbase + q;

        int2 offp = {0, 0};
        float4 wp = {0.f, 0.f, 0.f, 0.f};
        if (qq < M) {
            const int Wi = s_Wl[l];
            const int s0 = s_St[l];
            const float Wf = (float)Wi;
            const float2 o2 = *reinterpret_cast<const float2*>(
                &og[(size_t)qq * 480 + r * 2]);
            const float2 rf = *reinterpret_cast<const float2*>(
                &refp[(size_t)qq * 10 + l * 2]);
            const float a = s_attn[q][r];

            const float px = fmaf(rf.x, Wf, -0.5f) + o2.x;
            const float py = fmaf(rf.y, Wf, -0.5f) + o2.y;
            const float x0f = floorf(px);
            const float y0f = floorf(py);
            const float lx = px - x0f;
            const float ly = py - y0f;
            const int x0 = (int)x0f;
            const int y0 = (int)y0f;

            const float wx0v = (x0 >= 0 && x0 < Wi) ? (1.f - lx) : 0.f;
            const float wx1v = (x0 + 1 >= 0 && x0 + 1 < Wi) ? lx : 0.f;
            const float wy0v = (y0 >= 0 && y0 < Wi) ? (1.f - ly) : 0.f;
            const float wy1v = (y0 + 1 >= 0 && y0 + 1 < Wi) ? ly : 0.f;

            const int c0 = min(max(x0, 0), Wi - 2);
            const int r0 = min(max(y0, 0), Wi - 2);
            const float swx0 = (x0 == c0 ? wx0v : 0.f) + (x0 + 1 == c0 ? wx1v : 0.f);
            const float swx1 = (x0 == c0 + 1 ? wx0v : 0.f) + (x0 + 1 == c0 + 1 ? wx1v : 0.f);
            const float swy0 = (y0 == r0 ? wy0v : 0.f) + (y0 + 1 == r0 ? wy1v : 0.f);
            const float swy1 = (y0 == r0 + 1 ? wy0v : 0.f) + (y0 + 1 == r0 + 1 ? wy1v : 0.f);

            offp.x = (s0 + r0 * Wi + c0) * 512;
            offp.y = offp.x + Wi * 512;
            wp.x = a * swx0 * swy0;
            wp.y = a * swx1 * swy0;
            wp.z = a * swx0 * swy1;
            wp.w = a * swx1 * swy1;
        }
        s_off[t] = offp;
        s_w[t] = wp;
    }
    __syncthreads();

    const int qi  = tid >> 5;
    const int g   = tid & 31;
    const int h   = g >> 2;
    const int sub = g & 3;
    const int bq = qbase + qi;
    if (bq >= M) return;
    const int b = bq / L;

    const char* vb = (const char*)value + (size_t)b * L * 512 + h * 64 + sub * 16;

    float acc[8] = {};
    const int tb = qi * 160 + h * 20;
    #pragma unroll 2
    for (int p = 0; p < 20; ++p) {
        const int2 off = s_off[tb + p];
        const float4 w = s_w[tb + p];
        const int4 u00 = *reinterpret_cast<const int4*>(vb + off.x);
        const int4 u10 = *reinterpret_cast<const int4*>(vb + off.x + 512);
        const int4 u01 = *reinterpret_cast<const int4*>(vb + off.y);
        const int4 u11 = *reinterpret_cast<const int4*>(vb + off.y + 512);
        #define ACC4(u, wt)                                                        \
            acc[0] = fmaf(wt, __uint_as_float((unsigned)(u).x << 16), acc[0]);      \
            acc[1] = fmaf(wt, __uint_as_float((unsigned)(u).x & 0xffff0000u), acc[1]); \
            acc[2] = fmaf(wt, __uint_as_float((unsigned)(u).y << 16), acc[2]);      \
            acc[3] = fmaf(wt, __uint_as_float((unsigned)(u).y & 0xffff0000u), acc[3]); \
            acc[4] = fmaf(wt, __uint_as_float((unsigned)(u).z << 16), acc[4]);      \
            acc[5] = fmaf(wt, __uint_as_float((unsigned)(u).z & 0xffff0000u), acc[5]); \
            acc[6] = fmaf(wt, __uint_as_float((unsigned)(u).w << 16), acc[6]);      \
            acc[7] = fmaf(wt, __uint_as_float((unsigned)(u).w & 0xffff0000u), acc[7]);
        ACC4(u00, w.x)
        ACC4(u10, w.y)
        ACC4(u01, w.z)
        ACC4(u11, w.w)
        #undef ACC4
    }

    ushort_t o[8];
    #pragma unroll
    for (int i = 0; i < 8; ++i)
        o[i] = ((__hip_bfloat16_raw)__float2bfloat16(acc[i])).x;
    int4 pkt;
    pkt.x = (int)o[0] | ((int)o[1] << 16);
    pkt.y = (int)o[2] | ((int)o[3] << 16);
    pkt.z = (int)o[4] | ((int)o[5] << 16);
    pkt.w = (int)o[6] | ((int)o[7] << 16);
    *reinterpret_cast<int4*>((ushort_t*)out + (size_t)bq * 256 + h * 32 + sub * 8) = pkt;
}

// ---------------------------------------------------------------------------
template<bool DUAL>
__global__ __launch_bounds__(256) void ln_kernel(
    const float* __restrict__ y, const float* __restrict__ g,
    const float* __restrict__ bta, float* __restrict__ outf,
    bf16* __restrict__ outb)
{
    const int row = blockIdx.x;
    const int tid = threadIdx.x;
    float v = y[(size_t)row * 256 + tid];
    float s = v, ss = v * v;
    #pragma unroll
    for (int o = 32; o > 0; o >>= 1) {
        s += __shfl_down(s, o);
        ss += __shfl_down(ss, o);
    }
    __shared__ float red[8];
    const int wid = tid >> 6, lane = tid & 63;
    if (lane == 0) { red[wid] = s; red[4 + wid] = ss; }
    __syncthreads();
    const float S = red[0] + red[1] + red[2] + red[3];
    const float SS = red[4] + red[5] + red[6] + red[7];
    const float mean = S * (1.f / 256.f);
    const float var = SS * (1.f / 256.f) - mean * mean;
    const float rs = rsqrtf(var + 1e-5f);
    const float o = (v - mean) * rs * g[tid] + bta[tid];
    outf[(size_t)row * 256 + tid] = o;
    if (DUAL) outb[(size_t)row * 256 + tid] = __float2bfloat16(o);
}

// ---------------------------------------------------------------------------
extern "C" void kernel_launch(void* const* d_in, const int* in_sizes, int n_in,
                              void* d_out, int out_size, void* d_ws, size_t ws_size,
                              hipStream_t stream)
{
    const int B = 2, L = 13343, C = 256, FF = 2048;
    const int M = B * L;  // 26686

    const float* src  = (const float*)d_in[0];
    const float* pos  = (const float*)d_in[1];
    const float* refp = (const float*)d_in[2];
    const float* wv   = (const float*)d_in[3];
    const float* bv   = (const float*)d_in[4];
    const float* wo   = (const float*)d_in[5];
    const float* bo   = (const float*)d_in[6];
    const float* wa   = (const float*)d_in[7];
    const float* ba   = (const float*)d_in[8];
    const float* wout = (const float*)d_in[9];
    const float* bout = (const float*)d_in[10];
    const float* ln1g = (const float*)d_in[11];
    const float* ln1b = (const float*)d_in[12];
    const float* w1   = (const float*)d_in[13];
    const float* b1   = (const float*)d_in[14];
    const float* w2   = (const float*)d_in[15];
    const float* b2   = (const float*)d_in[16];
    const float* ln2g = (const float*)d_in[17];
    const float* ln2b = (const float*)d_in[18];

    char* ws = (char*)d_ws;
    const size_t MB = 1ull << 20;
    // ---- workspace overlay (peak ~184 MB) ----
    bf16*  src_b  = (bf16*)(ws + 0);         // 13.7 MB
    bf16*  q_b    = (bf16*)(ws + 14 * MB);   // 13.7
    bf16*  val_b  = (bf16*)(ws + 28 * MB);   // 13.7
    float* og     = (float*)(ws + 42 * MB);  // M*480 f32 = 51.2 -> ends 93.2
    bf16*  acc_b  = (bf16*)(ws + 95 * MB);   // 13.7 -> ends 108.7
    bf16*  h_b    = (bf16*)(ws + 0);         // M*2048 bf16 = 109.3 (overlays dead)
    float* y      = (float*)(ws + 110 * MB); // 27.3 (dead after LN1)
    float* z      = (float*)(ws + 110 * MB); // overlays y
    bf16*  x_b    = (bf16*)(ws + 138 * MB);  // 13.7
    float* x_f    = (float*)(ws + 152 * MB); // 27.3 -> ends 179.3
    bf16* wvt    = (bf16*)(ws + 180 * MB);   // 256*256
    bf16* wcat   = wvt + 256 * 256;          // 480*256
    bf16* woutt  = wcat + 480 * 256;         // 256*256
    bf16* w1t    = woutt + 256 * 256;        // 2048*256
    bf16* w2t    = w1t + 2048 * 256;         // 256*2048
    float* bcat  = (float*)(w2t + 256 * 2048); // 480 f32, ends ~182.6 MB
    (void)ws_size; (void)n_in; (void)in_sizes; (void)out_size;

    const int mt   = (M + 127) / 128;  // 209
    const int mt64 = (M + 63) / 64;    // 417

    // ---- fused weight prep (one launch) ----
    prep_kernel<<<1274, 256, 0, stream>>>(wv, wo, wa, wout, w1, w2, bo, ba,
                                          wvt, wcat, woutt, w1t, w2t, bcat);

    // ---- fused activation casts ----
    cast2_kernel<<<(M * C + 255) / 256, 256, 0, stream>>>(src, pos, src_b, q_b, M * C);

    // value = src @ wv + bv  (bf16)  [64x128 M-split tiles]
    gemm_mfma_s<false, true, false><<<dim3(2, mt64), 256, 0, stream>>>(
        (const ushort_t*)src_b, (const ushort_t*)wvt, bv, nullptr, val_b, M, 256, 256);

    // og = q @ [wo|wa] + [bo|ba]  (f32, N=480)
    gemm_mfma<false, false, false><<<dim3(4, mt), 256, 0, stream>>>(
        (const ushort_t*)q_b, (const ushort_t*)wcat, bcat, nullptr, og, M, 480, 256);

    // deformable attention -> acc_b (bf16)
    msda_kernel_v3<<<(M + 7) / 8, 256, 0, stream>>>(
        og, refp, (const ushort_t*)val_b, acc_b, M, L);

    // y = acc @ wout + bout + src  (f32)  [64x128 tiles]
    gemm_mfma_s<false, false, true><<<dim3(2, mt64), 256, 0, stream>>>(
        (const ushort_t*)acc_b, (const ushort_t*)woutt, bout, src, y, M, 256, 256);

    // x = LN1(y)
    ln_kernel<true><<<M, 256, 0, stream>>>(y, ln1g, ln1b, x_f, x_b);

    // h = relu(x @ w1 + b1)  (bf16)
    gemm_mfma<true, true, false><<<dim3(16, mt), 256, 0, stream>>>(
        (const ushort_t*)x_b, (const ushort_t*)w1t, b1, nullptr, h_b, M, FF, 256);

    // z = h @ w2 + b2 + x  (f32)  [64x128 tiles, K=2048]
    gemm_mfma_s<false, false, true><<<dim3(2, mt64), 256, 0, stream>>>(
        (const ushort_t*)h_b, (const ushort_t*)w2t, b2, x_f, z, M, 256, FF);

    // out = LN2(z)
    ln_kernel<false><<<M, 256, 0, stream>>>(z, ln2g, ln2b, (float*)d_out, nullptr);
}

// Round 12
// 410.704 us; speedup vs baseline: 2.3965x; 2.3965x over previous
//
#include <hip/hip_runtime.h>
#include <hip/hip_bf16.h>

typedef __hip_bfloat16 bf16;
typedef unsigned short ushort_t;
typedef __attribute__((ext_vector_type(8))) short bf16x8;
typedef __attribute__((ext_vector_type(16))) float f32x16;

__device__ __forceinline__ float us2f(unsigned short u) {
    unsigned int x = ((unsigned int)u) << 16;
    return __uint_as_float(x);
}
__device__ __forceinline__ ushort_t f2us(float f) {
    return ((__hip_bfloat16_raw)__float2bfloat16(f)).x;
}

// async global->LDS, 16 B per lane. LDS dest = wave-uniform base + lane*16.
__device__ __forceinline__ void gl_lds16(const ushort_t* g, ushort_t* l) {
    __builtin_amdgcn_global_load_lds(
        (const __attribute__((address_space(1))) void*)g,
        (__attribute__((address_space(3))) void*)l, 16, 0, 0);
}

// ---------------------------------------------------------------------------
// R10-proven vectorized epilogue (stride 34, SEPARATE tlds — NOT the R11
// union/stride-33 form, which caused 10x LDS conflicts + 4.5x regression).
// Used ONLY by the 128x128 variant (R10 evidence: helped gemm_mfma, hurt _s).
// ---------------------------------------------------------------------------
template<bool RELU, bool OUT_BF16, bool HAS_RESID>
__device__ __forceinline__ void epi_store_tile(
    float* __restrict__ tl, const f32x16& acc, int lane,
    int mbase, int nbase, const float* __restrict__ bias,
    const float* __restrict__ resid, void* __restrict__ outv, int M, int N)
{
    const int l32 = lane & 31, hi = lane >> 5;
    #pragma unroll
    for (int r = 0; r < 16; ++r) {
        const int row = (r & 3) + ((r >> 2) << 3) + hi * 4;
        tl[row * 34 + l32] = acc[r];
    }
    const int rr = lane >> 1;
    const int cc = (lane & 1) * 16;
    const int m  = mbase + rr;
    const int nb = nbase + cc;
    if (m >= M || nb >= N) return;

    if (OUT_BF16) {
        bf16* op = (bf16*)outv + (size_t)m * N + nb;
        #pragma unroll
        for (int gv = 0; gv < 2; ++gv) {
            unsigned pk[4];
            #pragma unroll
            for (int q = 0; q < 2; ++q) {
                const int c = cc + gv * 8 + q * 4;
                const float4 v  = *reinterpret_cast<const float4*>(&tl[rr * 34 + c]);
                const float4 b4 = *reinterpret_cast<const float4*>(&bias[nbase + c]);
                float o0 = v.x + b4.x, o1 = v.y + b4.y;
                float o2 = v.z + b4.z, o3 = v.w + b4.w;
                if (HAS_RESID) {
                    const float4 r4 = *reinterpret_cast<const float4*>(
                        &resid[(size_t)m * N + nbase + c]);
                    o0 += r4.x; o1 += r4.y; o2 += r4.z; o3 += r4.w;
                }
                if (RELU) {
                    o0 = fmaxf(o0, 0.f); o1 = fmaxf(o1, 0.f);
                    o2 = fmaxf(o2, 0.f); o3 = fmaxf(o3, 0.f);
                }
                pk[q * 2 + 0] = (unsigned)f2us(o0) | ((unsigned)f2us(o1) << 16);
                pk[q * 2 + 1] = (unsigned)f2us(o2) | ((unsigned)f2us(o3) << 16);
            }
            int4 w4; w4.x = pk[0]; w4.y = pk[1]; w4.z = pk[2]; w4.w = pk[3];
            *reinterpret_cast<int4*>(op + gv * 8) = w4;
        }
    } else {
        float* op = (float*)outv + (size_t)m * N + nb;
        #pragma unroll
        for (int q = 0; q < 4; ++q) {
            const int c = cc + q * 4;
            const float4 v  = *reinterpret_cast<const float4*>(&tl[rr * 34 + c]);
            const float4 b4 = *reinterpret_cast<const float4*>(&bias[nbase + c]);
            float4 o;
            o.x = v.x + b4.x; o.y = v.y + b4.y;
            o.z = v.z + b4.z; o.w = v.w + b4.w;
            if (HAS_RESID) {
                const float4 r4 = *reinterpret_cast<const float4*>(
                    &resid[(size_t)m * N + nbase + c]);
                o.x += r4.x; o.y += r4.y; o.z += r4.z; o.w += r4.w;
            }
            if (RELU) {
                o.x = fmaxf(o.x, 0.f); o.y = fmaxf(o.y, 0.f);
                o.z = fmaxf(o.z, 0.f); o.w = fmaxf(o.w, 0.f);
            }
            *reinterpret_cast<float4*>(op + q * 4) = o;
        }
    }
}

// ---------------------------------------------------------------------------
// Fused input cast (float4 vectorized): src_b = bf16(src), q_b = bf16(src+pos)
// ---------------------------------------------------------------------------
__global__ __launch_bounds__(256) void cast2_kernel(
    const float* __restrict__ src, const float* __restrict__ pos,
    bf16* __restrict__ src_b, bf16* __restrict__ q_b, int n)
{
    int i = (blockIdx.x * 256 + threadIdx.x) * 4;
    if (i < n) {
        const float4 s4 = *reinterpret_cast<const float4*>(&src[i]);
        const float4 p4 = *reinterpret_cast<const float4*>(&pos[i]);
        int2 sp, qp;
        sp.x = (unsigned)f2us(s4.x) | ((unsigned)f2us(s4.y) << 16);
        sp.y = (unsigned)f2us(s4.z) | ((unsigned)f2us(s4.w) << 16);
        qp.x = (unsigned)f2us(s4.x + p4.x) | ((unsigned)f2us(s4.y + p4.y) << 16);
        qp.y = (unsigned)f2us(s4.z + p4.z) | ((unsigned)f2us(s4.w + p4.w) << 16);
        *reinterpret_cast<int2*>((ushort_t*)src_b + i) = sp;
        *reinterpret_cast<int2*>((ushort_t*)q_b + i) = qp;
    }
}

// ---------------------------------------------------------------------------
// Fused weight prep: all transpose-casts + bias concat in ONE launch.
// ---------------------------------------------------------------------------
__global__ __launch_bounds__(256) void prep_kernel(
    const float* __restrict__ wv, const float* __restrict__ wo,
    const float* __restrict__ wa, const float* __restrict__ wout,
    const float* __restrict__ w1, const float* __restrict__ w2,
    const float* __restrict__ bo, const float* __restrict__ ba,
    bf16* __restrict__ wvt, bf16* __restrict__ wcat, bf16* __restrict__ woutt,
    bf16* __restrict__ w1t, bf16* __restrict__ w2t, float* __restrict__ bcat)
{
    __shared__ float tile[32][33];
    const int b = blockIdx.x;
    const float* W; bf16* Wt; int K, N, tb;
    if (b < 64)        { W = wv;   Wt = wvt;            K = 256;  N = 256;  tb = b; }
    else if (b < 144)  { W = wo;   Wt = wcat;           K = 256;  N = 320;  tb = b - 64; }
    else if (b < 184)  { W = wa;   Wt = wcat + 320*256; K = 256;  N = 160;  tb = b - 144; }
    else if (b < 248)  { W = wout; Wt = woutt;          K = 256;  N = 256;  tb = b - 184; }
    else if (b < 760)  { W = w1;   Wt = w1t;            K = 256;  N = 2048; tb = b - 248; }
    else if (b < 1272) { W = w2;   Wt = w2t;            K = 2048; N = 256;  tb = b - 760; }
    else {
        int i = (b - 1272) * 256 + threadIdx.x;
        if (i < 320) bcat[i] = bo[i];
        else if (i < 480) bcat[i] = ba[i - 320];
        return;
    }
    const int ntn = N >> 5;
    const int nb = (tb % ntn) * 32, kb = (tb / ntn) * 32;
    const int tx = threadIdx.x & 31, ty = threadIdx.x >> 5;  // 32 x 8
    #pragma unroll
    for (int i = 0; i < 32; i += 8) {
        int k = kb + ty + i, n = nb + tx;
        tile[ty + i][tx] = (k < K && n < N) ? W[(size_t)k * N + n] : 0.f;
    }
    __syncthreads();
    #pragma unroll
    for (int i = 0; i < 32; i += 8) {
        int n = nb + ty + i, k = kb + tx;
        if (n < N && k < K)
            Wt[(size_t)n * K + k] = __float2bfloat16(tile[tx][ty + i]);
    }
}

// ---------------------------------------------------------------------------
// MFMA bf16 GEMM (128x128 tile): for og (N=480) and FFN1 (N=2048).
// R10 form: separate tlds epilogue (stride 34).
// ---------------------------------------------------------------------------
template<bool RELU, bool OUT_BF16, bool HAS_RESID>
__global__ __launch_bounds__(256, 4) void gemm_mfma(
    const ushort_t* __restrict__ A,    // [M][K] bf16
    const ushort_t* __restrict__ Bt,   // [N][K] bf16
    const float* __restrict__ bias,    // [N] f32
    const float* __restrict__ resid,   // [M][N] f32
    void* __restrict__ outv, int M, int N, int K)
{
    __shared__ ushort_t Asmem[128 * 32];
    __shared__ ushort_t Bsmem[128 * 32];
    __shared__ float tlds[4][32 * 34];
    const int tid = threadIdx.x;
    const int lane = tid & 63;
    const int wave = tid >> 6;
    const int l32 = lane & 31;
    const int hi  = lane >> 5;
    const int wm = wave >> 1, wn = wave & 1;
    const int m0 = blockIdx.y * 128;
    const int n0 = blockIdx.x * 128;

    const int srow = lane >> 2;
    const int sch  = (lane & 3) * 8;

    const ushort_t* aP[2]; const ushort_t* bP[2];
    ushort_t* aL[2]; ushort_t* bL[2];
    #pragma unroll
    for (int i = 0; i < 2; ++i) {
        const int rbase = wave * 32 + i * 16;
        int mA = m0 + rbase + srow; if (mA > M - 1) mA = M - 1;
        int nB = n0 + rbase + srow; if (nB > N - 1) nB = N - 1;
        aP[i] = A  + (size_t)mA * K + sch;
        bP[i] = Bt + (size_t)nB * K + sch;
        aL[i] = &Asmem[rbase * 32];
        bL[i] = &Bsmem[rbase * 32];
    }

    f32x16 acc[2][2] = {};

    for (int k0 = 0; k0 < K; k0 += 32) {
        #pragma unroll
        for (int i = 0; i < 2; ++i) {
            gl_lds16(aP[i], aL[i]);
            gl_lds16(bP[i], bL[i]);
            aP[i] += 32; bP[i] += 32;
        }
        __syncthreads();

        #pragma unroll
        for (int kw = 0; kw < 2; ++kw) {
            bf16x8 af[2], bfr[2];
            #pragma unroll
            for (int i = 0; i < 2; ++i) {
                const int rowA = wm * 64 + i * 32 + l32;
                af[i] = *reinterpret_cast<const bf16x8*>(
                    &Asmem[rowA * 32 + kw * 16 + hi * 8]);
                const int rowB = wn * 64 + i * 32 + l32;
                bfr[i] = *reinterpret_cast<const bf16x8*>(
                    &Bsmem[rowB * 32 + kw * 16 + hi * 8]);
            }
            #pragma unroll
            for (int i = 0; i < 2; ++i)
                #pragma unroll
                for (int j = 0; j < 2; ++j)
                    acc[i][j] = __builtin_amdgcn_mfma_f32_32x32x16_bf16(
                        af[i], bfr[j], acc[i][j], 0, 0, 0);
        }
        __syncthreads();
    }

    float* tl = &tlds[wave][0];
    #pragma unroll
    for (int i = 0; i < 2; ++i)
        #pragma unroll
        for (int j = 0; j < 2; ++j)
            epi_store_tile<RELU, OUT_BF16, HAS_RESID>(
                tl, acc[i][j], lane,
                m0 + wm * 64 + i * 32, n0 + wn * 64 + j * 32,
                bias, resid, outv, M, N);
}

// ---------------------------------------------------------------------------
// MFMA bf16 GEMM (64x128 tile, M-split): for N=256 GEMMs. EXACT R9 form
// (scalar epilogue — R10/R11 LDS epilogues both regressed this variant).
// ---------------------------------------------------------------------------
template<bool RELU, bool OUT_BF16, bool HAS_RESID>
__global__ __launch_bounds__(256, 4) void gemm_mfma_s(
    const ushort_t* __restrict__ A,    // [M][K] bf16
    const ushort_t* __restrict__ Bt,   // [N][K] bf16
    const float* __restrict__ bias,    // [N] f32
    const float* __restrict__ resid,   // [M][N] f32
    void* __restrict__ outv, int M, int N, int K)
{
    __shared__ ushort_t Asmem[64 * 32];
    __shared__ ushort_t Bsmem[128 * 32];
    const int tid = threadIdx.x;
    const int lane = tid & 63;
    const int wave = tid >> 6;
    const int l32 = lane & 31;
    const int hi  = lane >> 5;
    const int wm = wave >> 1;
    const int wn = wave & 1;
    const int m0 = blockIdx.y * 64;
    const int n0 = blockIdx.x * 128;

    const int srow = lane >> 2;
    const int sch  = (lane & 3) * 8;

    int mA = m0 + wave * 16 + srow; if (mA > M - 1) mA = M - 1;
    const ushort_t* aP = A + (size_t)mA * K + sch;
    ushort_t* aL = &Asmem[(wave * 16) * 32];
    const ushort_t* bP[2]; ushort_t* bL[2];
    #pragma unroll
    for (int i = 0; i < 2; ++i) {
        const int rbase = wave * 32 + i * 16;
        int nB = n0 + rbase + srow; if (nB > N - 1) nB = N - 1;
        bP[i] = Bt + (size_t)nB * K + sch;
        bL[i] = &Bsmem[rbase * 32];
    }

    f32x16 acc[2] = {};

    for (int k0 = 0; k0 < K; k0 += 32) {
        gl_lds16(aP, aL);       aP    += 32;
        gl_lds16(bP[0], bL[0]); bP[0] += 32;
        gl_lds16(bP[1], bL[1]); bP[1] += 32;
        __syncthreads();

        #pragma unroll
        for (int kw = 0; kw < 2; ++kw) {
            const bf16x8 af = *reinterpret_cast<const bf16x8*>(
                &Asmem[(wm * 32 + l32) * 32 + kw * 16 + hi * 8]);
            bf16x8 bfr[2];
            #pragma unroll
            for (int j = 0; j < 2; ++j) {
                const int rowB = wn * 64 + j * 32 + l32;
                bfr[j] = *reinterpret_cast<const bf16x8*>(
                    &Bsmem[rowB * 32 + kw * 16 + hi * 8]);
            }
            #pragma unroll
            for (int j = 0; j < 2; ++j)
                acc[j] = __builtin_amdgcn_mfma_f32_32x32x16_bf16(
                    af, bfr[j], acc[j], 0, 0, 0);
        }
        __syncthreads();
    }

    const int mb = m0 + wm * 32 + hi * 4;
    #pragma unroll
    for (int j = 0; j < 2; ++j) {
        const int n = n0 + wn * 64 + j * 32 + l32;
        if (n >= N) continue;
        const float bval = bias[n];
        #pragma unroll
        for (int r = 0; r < 16; ++r) {
            const int m = mb + (r & 3) + (r >> 2) * 8;
            if (m >= M) continue;
            float v = acc[j][r] + bval;
            if (HAS_RESID) v += resid[(size_t)m * N + n];
            if (RELU) v = fmaxf(v, 0.f);
            if (OUT_BF16)
                ((bf16*)outv)[(size_t)m * N + n] = __float2bfloat16(v);
            else
                ((float*)outv)[(size_t)m * N + n] = v;
        }
    }
}

// ---------------------------------------------------------------------------
// MS-deformable attention v3 (og now bf16).
// ---------------------------------------------------------------------------
__global__ __launch_bounds__(256) void msda_kernel_v3(
    const ushort_t* __restrict__ og,     // [M,480] bf16: offs 0..319, logits 320..479
    const float* __restrict__ refp,      // [M,10]
    const ushort_t* __restrict__ value,  // [M,256] bf16 = (B,L,H,32)
    bf16* __restrict__ out,              // [M,256] bf16
    int M, int L)
{
    const int tid = threadIdx.x;
    const int qbase = blockIdx.x * 8;

    __shared__ float  s_attn[8][160];
    __shared__ int2   s_off[1280];
    __shared__ float4 s_w[1280];
    __shared__ int    s_Wl[5], s_St[5];

    if (tid < 5) {
        const int HW[5] = {100, 50, 25, 13, 7};
        const int st[5] = {0, 10000, 12500, 13125, 13294};
        s_Wl[tid] = HW[tid];
        s_St[tid] = st[tid];
    }

    for (int i = tid; i < 1280; i += 256) {
        int q = i / 160, j = i - q * 160;
        int qq = qbase + q;
        s_attn[q][j] = (qq < M) ? us2f(og[(size_t)qq * 480 + 320 + j]) : 0.f;
    }
    __syncthreads();

    if (tid < 64) {
        float* a = &s_attn[tid >> 3][(tid & 7) * 20];
        float mx = -1e30f;
        #pragma unroll
        for (int i = 0; i < 20; ++i) mx = fmaxf(mx, a[i]);
        float ssum = 0.f;
        #pragma unroll
        for (int i = 0; i < 20; ++i) {
            float e = __expf(a[i] - mx);
            a[i] = e;
            ssum += e;
        }
        float inv = 1.f / ssum;
        #pragma unroll
        for (int i = 0; i < 20; ++i) a[i] *= inv;
    }
    __syncthreads();

    #pragma unroll
    for (int it = 0; it < 5; ++it) {
        const int t = tid + it * 256;
        const int q  = t / 160;
        const int r  = t - q * 160;
        const int l  = (r - (r / 20) * 20) >> 2;
        const int qq = qbase + q;

        int2 offp = {0, 0};
        float4 wp = {0.f, 0.f, 0.f, 0.f};
        if (qq < M) {
            const int Wi = s_Wl[l];
            const int s0 = s_St[l];
            const float Wf = (float)Wi;
            const float ox = us2f(og[(size_t)qq * 480 + r * 2]);
            const float oy = us2f(og[(size_t)qq * 480 + r * 2 + 1]);
            const float2 rf = *reinterpret_cast<const float2*>(
                &refp[(size_t)qq * 10 + l * 2]);
            const float a = s_attn[q][r];

            const float px = fmaf(rf.x, Wf, -0.5f) + ox;
            const float py = fmaf(rf.y, Wf, -0.5f) + oy;
            const float x0f = floorf(px);
            const float y0f = floorf(py);
            const float lx = px - x0f;
            const float ly = py - y0f;
            const int x0 = (int)x0f;
            const int y0 = (int)y0f;

            const float wx0v = (x0 >= 0 && x0 < Wi) ? (1.f - lx) : 0.f;
            const float wx1v = (x0 + 1 >= 0 && x0 + 1 < Wi) ? lx : 0.f;
            const float wy0v = (y0 >= 0 && y0 < Wi) ? (1.f - ly) : 0.f;
            const float wy1v = (y0 + 1 >= 0 && y0 + 1 < Wi) ? ly : 0.f;

            const int c0 = min(max(x0, 0), Wi - 2);
            const int r0 = min(max(y0, 0), Wi - 2);
            const float swx0 = (x0 == c0 ? wx0v : 0.f) + (x0 + 1 == c0 ? wx1v : 0.f);
            const float swx1 = (x0 == c0 + 1 ? wx0v : 0.f) + (x0 + 1 == c0 + 1 ? wx1v : 0.f);
            const float swy0 = (y0 == r0 ? wy0v : 0.f) + (y0 + 1 == r0 ? wy1v : 0.f);
            const float swy1 = (y0 == r0 + 1 ? wy0v : 0.f) + (y0 + 1 == r0 + 1 ? wy1v : 0.f);

            offp.x = (s0 + r0 * Wi + c0) * 512;
            offp.y = offp.x + Wi * 512;
            wp.x = a * swx0 * swy0;
            wp.y = a * swx1 * swy0;
            wp.z = a * swx0 * swy1;
            wp.w = a * swx1 * swy1;
        }
        s_off[t] = offp;
        s_w[t] = wp;
    }
    __syncthreads();

    const int qi  = tid >> 5;
    const int g   = tid & 31;
    const int h   = g >> 2;
    const int sub = g & 3;
    const int bq = qbase + qi;
    if (bq >= M) return;
    const int b = bq / L;

    const char* vb = (const char*)value + (size_t)b * L * 512 + h * 64 + sub * 16;

    float acc[8] = {};
    const int tb = qi * 160 + h * 20;
    #pragma unroll 2
    for (int p = 0; p < 20; ++p) {
        const int2 off = s_off[tb + p];
        const float4 w = s_w[tb + p];
        const int4 u00 = *reinterpret_cast<const int4*>(vb + off.x);
        const int4 u10 = *reinterpret_cast<const int4*>(vb + off.x + 512);
        const int4 u01 = *reinterpret_cast<const int4*>(vb + off.y);
        const int4 u11 = *reinterpret_cast<const int4*>(vb + off.y + 512);
        #define ACC4(u, wt)                                                        \
            acc[0] = fmaf(wt, __uint_as_float((unsigned)(u).x << 16), acc[0]);      \
            acc[1] = fmaf(wt, __uint_as_float((unsigned)(u).x & 0xffff0000u), acc[1]); \
            acc[2] = fmaf(wt, __uint_as_float((unsigned)(u).y << 16), acc[2]);      \
            acc[3] = fmaf(wt, __uint_as_float((unsigned)(u).y & 0xffff0000u), acc[3]); \
            acc[4] = fmaf(wt, __uint_as_float((unsigned)(u).z << 16), acc[4]);      \
            acc[5] = fmaf(wt, __uint_as_float((unsigned)(u).z & 0xffff0000u), acc[5]); \
            acc[6] = fmaf(wt, __uint_as_float((unsigned)(u).w << 16), acc[6]);      \
            acc[7] = fmaf(wt, __uint_as_float((unsigned)(u).w & 0xffff0000u), acc[7]);
        ACC4(u00, w.x)
        ACC4(u10, w.y)
        ACC4(u01, w.z)
        ACC4(u11, w.w)
        #undef ACC4
    }

    ushort_t o[8];
    #pragma unroll
    for (int i = 0; i < 8; ++i) o[i] = f2us(acc[i]);
    int4 pkt;
    pkt.x = (int)o[0] | ((int)o[1] << 16);
    pkt.y = (int)o[2] | ((int)o[3] << 16);
    pkt.z = (int)o[4] | ((int)o[5] << 16);
    pkt.w = (int)o[6] | ((int)o[7] << 16);
    *reinterpret_cast<int4*>((ushort_t*)out + (size_t)bq * 256 + h * 32 + sub * 8) = pkt;
}

// ---------------------------------------------------------------------------
// LayerNorm, vectorized: block = 4 waves = 4 rows; wave-per-row, float4 lane
// loads, shuffle-only reduction (no LDS, no barrier).
// ---------------------------------------------------------------------------
template<bool DUAL>
__global__ __launch_bounds__(256) void ln_kernel(
    const float* __restrict__ y, const float* __restrict__ g,
    const float* __restrict__ bta, float* __restrict__ outf,
    bf16* __restrict__ outb, int M)
{
    const int wave = threadIdx.x >> 6, lane = threadIdx.x & 63;
    const int row = blockIdx.x * 4 + wave;
    if (row >= M) return;
    const float4 v = *reinterpret_cast<const float4*>(&y[(size_t)row * 256 + lane * 4]);
    float s  = v.x + v.y + v.z + v.w;
    float ss = v.x * v.x + v.y * v.y + v.z * v.z + v.w * v.w;
    #pragma unroll
    for (int o = 32; o > 0; o >>= 1) {
        s += __shfl_down(s, o);
        ss += __shfl_down(ss, o);
    }
    s = __shfl(s, 0);
    ss = __shfl(ss, 0);
    const float mean = s * (1.f / 256.f);
    const float var = ss * (1.f / 256.f) - mean * mean;
    const float rs = rsqrtf(var + 1e-5f);
    const float4 g4 = *reinterpret_cast<const float4*>(&g[lane * 4]);
    const float4 b4 = *reinterpret_cast<const float4*>(&bta[lane * 4]);
    float4 o4;
    o4.x = (v.x - mean) * rs * g4.x + b4.x;
    o4.y = (v.y - mean) * rs * g4.y + b4.y;
    o4.z = (v.z - mean) * rs * g4.z + b4.z;
    o4.w = (v.w - mean) * rs * g4.w + b4.w;
    *reinterpret_cast<float4*>(&outf[(size_t)row * 256 + lane * 4]) = o4;
    if (DUAL) {
        int2 pk;
        pk.x = (unsigned)f2us(o4.x) | ((unsigned)f2us(o4.y) << 16);
        pk.y = (unsigned)f2us(o4.z) | ((unsigned)f2us(o4.w) << 16);
        *reinterpret_cast<int2*>((ushort_t*)outb + (size_t)row * 256 + lane * 4) = pk;
    }
}

// ---------------------------------------------------------------------------
extern "C" void kernel_launch(void* const* d_in, const int* in_sizes, int n_in,
                              void* d_out, int out_size, void* d_ws, size_t ws_size,
                              hipStream_t stream)
{
    const int B = 2, L = 13343, C = 256, FF = 2048;
    const int M = B * L;  // 26686

    const float* src  = (const float*)d_in[0];
    const float* pos  = (const float*)d_in[1];
    const float* refp = (const float*)d_in[2];
    const float* wv   = (const float*)d_in[3];
    const float* bv   = (const float*)d_in[4];
    const float* wo   = (const float*)d_in[5];
    const float* bo   = (const float*)d_in[6];
    const float* wa   = (const float*)d_in[7];
    const float* ba   = (const float*)d_in[8];
    const float* wout = (const float*)d_in[9];
    const float* bout = (const float*)d_in[10];
    const float* ln1g = (const float*)d_in[11];
    const float* ln1b = (const float*)d_in[12];
    const float* w1   = (const float*)d_in[13];
    const float* b1   = (const float*)d_in[14];
    const float* w2   = (const float*)d_in[15];
    const float* b2   = (const float*)d_in[16];
    const float* ln2g = (const float*)d_in[17];
    const float* ln2b = (const float*)d_in[18];

    char* ws = (char*)d_ws;
    const size_t MB = 1ull << 20;
    // ---- workspace overlay (peak ~184 MB) ----
    bf16*  src_b  = (bf16*)(ws + 0);         // 13.7 MB
    bf16*  q_b    = (bf16*)(ws + 14 * MB);   // 13.7
    bf16*  val_b  = (bf16*)(ws + 28 * MB);   // 13.7
    bf16*  og     = (bf16*)(ws + 42 * MB);   // M*480 bf16 = 25.6 -> ends 67.6
    bf16*  acc_b  = (bf16*)(ws + 95 * MB);   // 13.7 -> ends 108.7
    bf16*  h_b    = (bf16*)(ws + 0);         // M*2048 bf16 = 109.3 (overlays dead)
    float* y      = (float*)(ws + 110 * MB); // 27.3 (dead after LN1)
    float* z      = (float*)(ws + 110 * MB); // overlays y
    bf16*  x_b    = (bf16*)(ws + 138 * MB);  // 13.7
    float* x_f    = (float*)(ws + 152 * MB); // 27.3 -> ends 179.3
    bf16* wvt    = (bf16*)(ws + 180 * MB);   // 256*256
    bf16* wcat   = wvt + 256 * 256;          // 480*256
    bf16* woutt  = wcat + 480 * 256;         // 256*256
    bf16* w1t    = woutt + 256 * 256;        // 2048*256
    bf16* w2t    = w1t + 2048 * 256;         // 256*2048
    float* bcat  = (float*)(w2t + 256 * 2048); // 480 f32, ends ~182.6 MB
    (void)ws_size; (void)n_in; (void)in_sizes; (void)out_size;

    const int mt   = (M + 127) / 128;  // 209
    const int mt64 = (M + 63) / 64;    // 417
    const int lnb  = (M + 3) / 4;      // 6672

    // ---- fused weight prep (one launch) ----
    prep_kernel<<<1274, 256, 0, stream>>>(wv, wo, wa, wout, w1, w2, bo, ba,
                                          wvt, wcat, woutt, w1t, w2t, bcat);

    // ---- fused activation casts (float4) ----
    cast2_kernel<<<(M * C / 4 + 255) / 256, 256, 0, stream>>>(
        src, pos, src_b, q_b, M * C);

    // value = src @ wv + bv  (bf16)  [64x128 M-split tiles]
    gemm_mfma_s<false, true, false><<<dim3(2, mt64), 256, 0, stream>>>(
        (const ushort_t*)src_b, (const ushort_t*)wvt, bv, nullptr, val_b, M, 256, 256);

    // og = q @ [wo|wa] + [bo|ba]  (bf16, N=480)
    gemm_mfma<false, true, false><<<dim3(4, mt), 256, 0, stream>>>(
        (const ushort_t*)q_b, (const ushort_t*)wcat, bcat, nullptr, og, M, 480, 256);

    // deformable attention -> acc_b (bf16)
    msda_kernel_v3<<<(M + 7) / 8, 256, 0, stream>>>(
        (const ushort_t*)og, refp, (const ushort_t*)val_b, acc_b, M, L);

    // y = acc @ wout + bout + src  (f32)  [64x128 tiles]
    gemm_mfma_s<false, false, true><<<dim3(2, mt64), 256, 0, stream>>>(
        (const ushort_t*)acc_b, (const ushort_t*)woutt, bout, src, y, M, 256, 256);

    // x = LN1(y)
    ln_kernel<true><<<lnb, 256, 0, stream>>>(y, ln1g, ln1b, x_f, x_b, M);

    // h = relu(x @ w1 + b1)  (bf16)
    gemm_mfma<true, true, false><<<dim3(16, mt), 256, 0, stream>>>(
        (const ushort_t*)x_b, (const ushort_t*)w1t, b1, nullptr, h_b, M, FF, 256);

    // z = h @ w2 + b2 + x  (f32)  [64x128 tiles, K=2048]
    gemm_mfma_s<false, false, true><<<dim3(2, mt64), 256, 0, stream>>>(
        (const ushort_t*)h_b, (const ushort_t*)w2t, b2, x_f, z, M, 256, FF);

    // out = LN2(z)
    ln_kernel<false><<<lnb, 256, 0, stream>>>(z, ln2g, ln2b, (float*)d_out, nullptr, M);
}

// Round 13
// 398.973 us; speedup vs baseline: 2.4669x; 1.0294x over previous
//
#include <hip/hip_runtime.h>
#include <hip/hip_bf16.h>

typedef __hip_bfloat16 bf16;
typedef unsigned short ushort_t;
typedef __attribute__((ext_vector_type(8))) short bf16x8;
typedef __attribute__((ext_vector_type(16))) float f32x16;

__device__ __forceinline__ float us2f(unsigned short u) {
    unsigned int x = ((unsigned int)u) << 16;
    return __uint_as_float(x);
}
__device__ __forceinline__ ushort_t f2us(float f) {
    return ((__hip_bfloat16_raw)__float2bfloat16(f)).x;
}

// async global->LDS, 16 B per lane. LDS dest = wave-uniform base + lane*16.
__device__ __forceinline__ void gl_lds16(const ushort_t* g, ushort_t* l) {
    __builtin_amdgcn_global_load_lds(
        (const __attribute__((address_space(1))) void*)g,
        (__attribute__((address_space(3))) void*)l, 16, 0, 0);
}

// ---------------------------------------------------------------------------
// R10-proven vectorized epilogue (stride 34, SEPARATE tlds). 128x128 variant
// only (R11: union/stride-33 form caused 10x LDS conflicts — do not revive).
// ---------------------------------------------------------------------------
template<bool RELU, bool OUT_BF16, bool HAS_RESID>
__device__ __forceinline__ void epi_store_tile(
    float* __restrict__ tl, const f32x16& acc, int lane,
    int mbase, int nbase, const float* __restrict__ bias,
    const float* __restrict__ resid, void* __restrict__ outv, int M, int N)
{
    const int l32 = lane & 31, hi = lane >> 5;
    #pragma unroll
    for (int r = 0; r < 16; ++r) {
        const int row = (r & 3) + ((r >> 2) << 3) + hi * 4;
        tl[row * 34 + l32] = acc[r];
    }
    const int rr = lane >> 1;
    const int cc = (lane & 1) * 16;
    const int m  = mbase + rr;
    const int nb = nbase + cc;
    if (m >= M || nb >= N) return;

    if (OUT_BF16) {
        bf16* op = (bf16*)outv + (size_t)m * N + nb;
        #pragma unroll
        for (int gv = 0; gv < 2; ++gv) {
            unsigned pk[4];
            #pragma unroll
            for (int q = 0; q < 2; ++q) {
                const int c = cc + gv * 8 + q * 4;
                const float4 v  = *reinterpret_cast<const float4*>(&tl[rr * 34 + c]);
                const float4 b4 = *reinterpret_cast<const float4*>(&bias[nbase + c]);
                float o0 = v.x + b4.x, o1 = v.y + b4.y;
                float o2 = v.z + b4.z, o3 = v.w + b4.w;
                if (HAS_RESID) {
                    const float4 r4 = *reinterpret_cast<const float4*>(
                        &resid[(size_t)m * N + nbase + c]);
                    o0 += r4.x; o1 += r4.y; o2 += r4.z; o3 += r4.w;
                }
                if (RELU) {
                    o0 = fmaxf(o0, 0.f); o1 = fmaxf(o1, 0.f);
                    o2 = fmaxf(o2, 0.f); o3 = fmaxf(o3, 0.f);
                }
                pk[q * 2 + 0] = (unsigned)f2us(o0) | ((unsigned)f2us(o1) << 16);
                pk[q * 2 + 1] = (unsigned)f2us(o2) | ((unsigned)f2us(o3) << 16);
            }
            int4 w4; w4.x = pk[0]; w4.y = pk[1]; w4.z = pk[2]; w4.w = pk[3];
            *reinterpret_cast<int4*>(op + gv * 8) = w4;
        }
    } else {
        float* op = (float*)outv + (size_t)m * N + nb;
        #pragma unroll
        for (int q = 0; q < 4; ++q) {
            const int c = cc + q * 4;
            const float4 v  = *reinterpret_cast<const float4*>(&tl[rr * 34 + c]);
            const float4 b4 = *reinterpret_cast<const float4*>(&bias[nbase + c]);
            float4 o;
            o.x = v.x + b4.x; o.y = v.y + b4.y;
            o.z = v.z + b4.z; o.w = v.w + b4.w;
            if (HAS_RESID) {
                const float4 r4 = *reinterpret_cast<const float4*>(
                    &resid[(size_t)m * N + nbase + c]);
                o.x += r4.x; o.y += r4.y; o.z += r4.z; o.w += r4.w;
            }
            if (RELU) {
                o.x = fmaxf(o.x, 0.f); o.y = fmaxf(o.y, 0.f);
                o.z = fmaxf(o.z, 0.f); o.w = fmaxf(o.w, 0.f);
            }
            *reinterpret_cast<float4*>(op + q * 4) = o;
        }
    }
}

// ---------------------------------------------------------------------------
// Fused input cast (float4): src_b = bf16(src), q_b = bf16(src + pos)
// ---------------------------------------------------------------------------
__global__ __launch_bounds__(256) void cast2_kernel(
    const float* __restrict__ src, const float* __restrict__ pos,
    bf16* __restrict__ src_b, bf16* __restrict__ q_b, int n)
{
    int i = (blockIdx.x * 256 + threadIdx.x) * 4;
    if (i < n) {
        const float4 s4 = *reinterpret_cast<const float4*>(&src[i]);
        const float4 p4 = *reinterpret_cast<const float4*>(&pos[i]);
        int2 sp, qp;
        sp.x = (unsigned)f2us(s4.x) | ((unsigned)f2us(s4.y) << 16);
        sp.y = (unsigned)f2us(s4.z) | ((unsigned)f2us(s4.w) << 16);
        qp.x = (unsigned)f2us(s4.x + p4.x) | ((unsigned)f2us(s4.y + p4.y) << 16);
        qp.y = (unsigned)f2us(s4.z + p4.z) | ((unsigned)f2us(s4.w + p4.w) << 16);
        *reinterpret_cast<int2*>((ushort_t*)src_b + i) = sp;
        *reinterpret_cast<int2*>((ushort_t*)q_b + i) = qp;
    }
}

// ---------------------------------------------------------------------------
// Fused weight prep: all transpose-casts + bias concat in ONE launch.
// ---------------------------------------------------------------------------
__global__ __launch_bounds__(256) void prep_kernel(
    const float* __restrict__ wv, const float* __restrict__ wo,
    const float* __restrict__ wa, const float* __restrict__ wout,
    const float* __restrict__ w1, const float* __restrict__ w2,
    const float* __restrict__ bo, const float* __restrict__ ba,
    bf16* __restrict__ wvt, bf16* __restrict__ wcat, bf16* __restrict__ woutt,
    bf16* __restrict__ w1t, bf16* __restrict__ w2t, float* __restrict__ bcat)
{
    __shared__ float tile[32][33];
    const int b = blockIdx.x;
    const float* W; bf16* Wt; int K, N, tb;
    if (b < 64)        { W = wv;   Wt = wvt;            K = 256;  N = 256;  tb = b; }
    else if (b < 144)  { W = wo;   Wt = wcat;           K = 256;  N = 320;  tb = b - 64; }
    else if (b < 184)  { W = wa;   Wt = wcat + 320*256; K = 256;  N = 160;  tb = b - 144; }
    else if (b < 248)  { W = wout; Wt = woutt;          K = 256;  N = 256;  tb = b - 184; }
    else if (b < 760)  { W = w1;   Wt = w1t;            K = 256;  N = 2048; tb = b - 248; }
    else if (b < 1272) { W = w2;   Wt = w2t;            K = 2048; N = 256;  tb = b - 760; }
    else {
        int i = (b - 1272) * 256 + threadIdx.x;
        if (i < 320) bcat[i] = bo[i];
        else if (i < 480) bcat[i] = ba[i - 320];
        return;
    }
    const int ntn = N >> 5;
    const int nb = (tb % ntn) * 32, kb = (tb / ntn) * 32;
    const int tx = threadIdx.x & 31, ty = threadIdx.x >> 5;  // 32 x 8
    #pragma unroll
    for (int i = 0; i < 32; i += 8) {
        int k = kb + ty + i, n = nb + tx;
        tile[ty + i][tx] = (k < K && n < N) ? W[(size_t)k * N + n] : 0.f;
    }
    __syncthreads();
    #pragma unroll
    for (int i = 0; i < 32; i += 8) {
        int n = nb + ty + i, k = kb + tx;
        if (n < N && k < K)
            Wt[(size_t)n * K + k] = __float2bfloat16(tile[tx][ty + i]);
    }
}

// ---------------------------------------------------------------------------
// MFMA bf16 GEMM (128x128 tile): for og (N=480) and FFN1 (N=2048).
// ---------------------------------------------------------------------------
template<bool RELU, bool OUT_BF16, bool HAS_RESID>
__global__ __launch_bounds__(256, 4) void gemm_mfma(
    const ushort_t* __restrict__ A,    // [M][K] bf16
    const ushort_t* __restrict__ Bt,   // [N][K] bf16
    const float* __restrict__ bias,    // [N] f32
    const float* __restrict__ resid,   // [M][N] f32
    void* __restrict__ outv, int M, int N, int K)
{
    __shared__ ushort_t Asmem[128 * 32];
    __shared__ ushort_t Bsmem[128 * 32];
    __shared__ float tlds[4][32 * 34];
    const int tid = threadIdx.x;
    const int lane = tid & 63;
    const int wave = tid >> 6;
    const int l32 = lane & 31;
    const int hi  = lane >> 5;
    const int wm = wave >> 1, wn = wave & 1;
    const int m0 = blockIdx.y * 128;
    const int n0 = blockIdx.x * 128;

    const int srow = lane >> 2;
    const int sch  = (lane & 3) * 8;

    const ushort_t* aP[2]; const ushort_t* bP[2];
    ushort_t* aL[2]; ushort_t* bL[2];
    #pragma unroll
    for (int i = 0; i < 2; ++i) {
        const int rbase = wave * 32 + i * 16;
        int mA = m0 + rbase + srow; if (mA > M - 1) mA = M - 1;
        int nB = n0 + rbase + srow; if (nB > N - 1) nB = N - 1;
        aP[i] = A  + (size_t)mA * K + sch;
        bP[i] = Bt + (size_t)nB * K + sch;
        aL[i] = &Asmem[rbase * 32];
        bL[i] = &Bsmem[rbase * 32];
    }

    f32x16 acc[2][2] = {};

    for (int k0 = 0; k0 < K; k0 += 32) {
        #pragma unroll
        for (int i = 0; i < 2; ++i) {
            gl_lds16(aP[i], aL[i]);
            gl_lds16(bP[i], bL[i]);
            aP[i] += 32; bP[i] += 32;
        }
        __syncthreads();

        #pragma unroll
        for (int kw = 0; kw < 2; ++kw) {
            bf16x8 af[2], bfr[2];
            #pragma unroll
            for (int i = 0; i < 2; ++i) {
                const int rowA = wm * 64 + i * 32 + l32;
                af[i] = *reinterpret_cast<const bf16x8*>(
                    &Asmem[rowA * 32 + kw * 16 + hi * 8]);
                const int rowB = wn * 64 + i * 32 + l32;
                bfr[i] = *reinterpret_cast<const bf16x8*>(
                    &Bsmem[rowB * 32 + kw * 16 + hi * 8]);
            }
            #pragma unroll
            for (int i = 0; i < 2; ++i)
                #pragma unroll
                for (int j = 0; j < 2; ++j)
                    acc[i][j] = __builtin_amdgcn_mfma_f32_32x32x16_bf16(
                        af[i], bfr[j], acc[i][j], 0, 0, 0);
        }
        __syncthreads();
    }

    float* tl = &tlds[wave][0];
    #pragma unroll
    for (int i = 0; i < 2; ++i)
        #pragma unroll
        for (int j = 0; j < 2; ++j)
            epi_store_tile<RELU, OUT_BF16, HAS_RESID>(
                tl, acc[i][j], lane,
                m0 + wm * 64 + i * 32, n0 + wn * 64 + j * 32,
                bias, resid, outv, M, N);
}

// ---------------------------------------------------------------------------
// MFMA bf16 GEMM (64x128 tile, M-split): N=256 GEMMs. R9 core + scalar
// epilogue. NEW: 1-D grid with XCD pair-swizzle — the two n-tiles of one
// m-tile sit 8 blocks apart => same XCD under %8 round-robin => 2nd block's
// A-rows (h for FFN2) hit that XCD's L2. RESID_BF16 for bf16 residuals.
// ---------------------------------------------------------------------------
template<bool RELU, bool OUT_BF16, bool HAS_RESID, bool RESID_BF16>
__global__ __launch_bounds__(256, 4) void gemm_mfma_s(
    const ushort_t* __restrict__ A,    // [M][K] bf16
    const ushort_t* __restrict__ Bt,   // [N][K] bf16
    const float* __restrict__ bias,    // [N] f32
    const void* __restrict__ residv,   // [M][N] f32 or bf16
    void* __restrict__ outv, int M, int N, int K, int mtiles)
{
    __shared__ ushort_t Asmem[64 * 32];
    __shared__ ushort_t Bsmem[128 * 32];
    const int lid = blockIdx.x;
    const int xb = (lid >> 3) & 1;
    const int yg = ((lid >> 4) << 3) | (lid & 7);
    if (yg >= mtiles) return;
    const int m0 = yg * 64;
    const int n0 = xb * 128;

    const int tid = threadIdx.x;
    const int lane = tid & 63;
    const int wave = tid >> 6;
    const int l32 = lane & 31;
    const int hi  = lane >> 5;
    const int wm = wave >> 1;
    const int wn = wave & 1;

    const int srow = lane >> 2;
    const int sch  = (lane & 3) * 8;

    int mA = m0 + wave * 16 + srow; if (mA > M - 1) mA = M - 1;
    const ushort_t* aP = A + (size_t)mA * K + sch;
    ushort_t* aL = &Asmem[(wave * 16) * 32];
    const ushort_t* bP[2]; ushort_t* bL[2];
    #pragma unroll
    for (int i = 0; i < 2; ++i) {
        const int rbase = wave * 32 + i * 16;
        int nB = n0 + rbase + srow; if (nB > N - 1) nB = N - 1;
        bP[i] = Bt + (size_t)nB * K + sch;
        bL[i] = &Bsmem[rbase * 32];
    }

    f32x16 acc[2] = {};

    for (int k0 = 0; k0 < K; k0 += 32) {
        gl_lds16(aP, aL);       aP    += 32;
        gl_lds16(bP[0], bL[0]); bP[0] += 32;
        gl_lds16(bP[1], bL[1]); bP[1] += 32;
        __syncthreads();

        #pragma unroll
        for (int kw = 0; kw < 2; ++kw) {
            const bf16x8 af = *reinterpret_cast<const bf16x8*>(
                &Asmem[(wm * 32 + l32) * 32 + kw * 16 + hi * 8]);
            bf16x8 bfr[2];
            #pragma unroll
            for (int j = 0; j < 2; ++j) {
                const int rowB = wn * 64 + j * 32 + l32;
                bfr[j] = *reinterpret_cast<const bf16x8*>(
                    &Bsmem[rowB * 32 + kw * 16 + hi * 8]);
            }
            #pragma unroll
            for (int j = 0; j < 2; ++j)
                acc[j] = __builtin_amdgcn_mfma_f32_32x32x16_bf16(
                    af, bfr[j], acc[j], 0, 0, 0);
        }
        __syncthreads();
    }

    const int mb = m0 + wm * 32 + hi * 4;
    #pragma unroll
    for (int j = 0; j < 2; ++j) {
        const int n = n0 + wn * 64 + j * 32 + l32;
        if (n >= N) continue;
        const float bval = bias[n];
        #pragma unroll
        for (int r = 0; r < 16; ++r) {
            const int m = mb + (r & 3) + (r >> 2) * 8;
            if (m >= M) continue;
            float v = acc[j][r] + bval;
            if (HAS_RESID) {
                if (RESID_BF16)
                    v += us2f(((const ushort_t*)residv)[(size_t)m * N + n]);
                else
                    v += ((const float*)residv)[(size_t)m * N + n];
            }
            if (RELU) v = fmaxf(v, 0.f);
            if (OUT_BF16)
                ((bf16*)outv)[(size_t)m * N + n] = __float2bfloat16(v);
            else
                ((float*)outv)[(size_t)m * N + n] = v;
        }
    }
}

// ---------------------------------------------------------------------------
// MS-deformable attention v3 (og bf16).
// ---------------------------------------------------------------------------
__global__ __launch_bounds__(256) void msda_kernel_v3(
    const ushort_t* __restrict__ og,     // [M,480] bf16: offs 0..319, logits 320..479
    const float* __restrict__ refp,      // [M,10]
    const ushort_t* __restrict__ value,  // [M,256] bf16 = (B,L,H,32)
    bf16* __restrict__ out,              // [M,256] bf16
    int M, int L)
{
    const int tid = threadIdx.x;
    const int qbase = blockIdx.x * 8;

    __shared__ float  s_attn[8][160];
    __shared__ int2   s_off[1280];
    __shared__ float4 s_w[1280];
    __shared__ int    s_Wl[5], s_St[5];

    if (tid < 5) {
        const int HW[5] = {100, 50, 25, 13, 7};
        const int st[5] = {0, 10000, 12500, 13125, 13294};
        s_Wl[tid] = HW[tid];
        s_St[tid] = st[tid];
    }

    for (int i = tid; i < 1280; i += 256) {
        int q = i / 160, j = i - q * 160;
        int qq = qbase + q;
        s_attn[q][j] = (qq < M) ? us2f(og[(size_t)qq * 480 + 320 + j]) : 0.f;
    }
    __syncthreads();

    if (tid < 64) {
        float* a = &s_attn[tid >> 3][(tid & 7) * 20];
        float mx = -1e30f;
        #pragma unroll
        for (int i = 0; i < 20; ++i) mx = fmaxf(mx, a[i]);
        float ssum = 0.f;
        #pragma unroll
        for (int i = 0; i < 20; ++i) {
            float e = __expf(a[i] - mx);
            a[i] = e;
            ssum += e;
        }
        float inv = 1.f / ssum;
        #pragma unroll
        for (int i = 0; i < 20; ++i) a[i] *= inv;
    }
    __syncthreads();

    #pragma unroll
    for (int it = 0; it < 5; ++it) {
        const int t = tid + it * 256;
        const int q  = t / 160;
        const int r  = t - q * 160;
        const int l  = (r - (r / 20) * 20) >> 2;
        const int qq = qbase + q;

        int2 offp = {0, 0};
        float4 wp = {0.f, 0.f, 0.f, 0.f};
        if (qq < M) {
            const int Wi = s_Wl[l];
            const int s0 = s_St[l];
            const float Wf = (float)Wi;
            const float ox = us2f(og[(size_t)qq * 480 + r * 2]);
            const float oy = us2f(og[(size_t)qq * 480 + r * 2 + 1]);
            const float2 rf = *reinterpret_cast<const float2*>(
                &refp[(size_t)qq * 10 + l * 2]);
            const float a = s_attn[q][r];

            const float px = fmaf(rf.x, Wf, -0.5f) + ox;
            const float py = fmaf(rf.y, Wf, -0.5f) + oy;
            const float x0f = floorf(px);
            const float y0f = floorf(py);
            const float lx = px - x0f;
            const float ly = py - y0f;
            const int x0 = (int)x0f;
            const int y0 = (int)y0f;

            const float wx0v = (x0 >= 0 && x0 < Wi) ? (1.f - lx) : 0.f;
            const float wx1v = (x0 + 1 >= 0 && x0 + 1 < Wi) ? lx : 0.f;
            const float wy0v = (y0 >= 0 && y0 < Wi) ? (1.f - ly) : 0.f;
            const float wy1v = (y0 + 1 >= 0 && y0 + 1 < Wi) ? ly : 0.f;

            const int c0 = min(max(x0, 0), Wi - 2);
            const int r0 = min(max(y0, 0), Wi - 2);
            const float swx0 = (x0 == c0 ? wx0v : 0.f) + (x0 + 1 == c0 ? wx1v : 0.f);
            const float swx1 = (x0 == c0 + 1 ? wx0v : 0.f) + (x0 + 1 == c0 + 1 ? wx1v : 0.f);
            const float swy0 = (y0 == r0 ? wy0v : 0.f) + (y0 + 1 == r0 ? wy1v : 0.f);
            const float swy1 = (y0 == r0 + 1 ? wy0v : 0.f) + (y0 + 1 == r0 + 1 ? wy1v : 0.f);

            offp.x = (s0 + r0 * Wi + c0) * 512;
            offp.y = offp.x + Wi * 512;
            wp.x = a * swx0 * swy0;
            wp.y = a * swx1 * swy0;
            wp.z = a * swx0 * swy1;
            wp.w = a * swx1 * swy1;
        }
        s_off[t] = offp;
        s_w[t] = wp;
    }
    __syncthreads();

    const int qi  = tid >> 5;
    const int g   = tid & 31;
    const int h   = g >> 2;
    const int sub = g & 3;
    const int bq = qbase + qi;
    if (bq >= M) return;
    const int b = bq / L;

    const char* vb = (const char*)value + (size_t)b * L * 512 + h * 64 + sub * 16;

    float acc[8] = {};
    const int tb = qi * 160 + h * 20;
    #pragma unroll 2
    for (int p = 0; p < 20; ++p) {
        const int2 off = s_off[tb + p];
        const float4 w = s_w[tb + p];
        const int4 u00 = *reinterpret_cast<const int4*>(vb + off.x);
        const int4 u10 = *reinterpret_cast<const int4*>(vb + off.x + 512);
        const int4 u01 = *reinterpret_cast<const int4*>(vb + off.y);
        const int4 u11 = *reinterpret_cast<const int4*>(vb + off.y + 512);
        #define ACC4(u, wt)                                                        \
            acc[0] = fmaf(wt, __uint_as_float((unsigned)(u).x << 16), acc[0]);      \
            acc[1] = fmaf(wt, __uint_as_float((unsigned)(u).x & 0xffff0000u), acc[1]); \
            acc[2] = fmaf(wt, __uint_as_float((unsigned)(u).y << 16), acc[2]);      \
            acc[3] = fmaf(wt, __uint_as_float((unsigned)(u).y & 0xffff0000u), acc[3]); \
            acc[4] = fmaf(wt, __uint_as_float((unsigned)(u).z << 16), acc[4]);      \
            acc[5] = fmaf(wt, __uint_as_float((unsigned)(u).z & 0xffff0000u), acc[5]); \
            acc[6] = fmaf(wt, __uint_as_float((unsigned)(u).w << 16), acc[6]);      \
            acc[7] = fmaf(wt, __uint_as_float((unsigned)(u).w & 0xffff0000u), acc[7]);
        ACC4(u00, w.x)
        ACC4(u10, w.y)
        ACC4(u01, w.z)
        ACC4(u11, w.w)
        #undef ACC4
    }

    ushort_t o[8];
    #pragma unroll
    for (int i = 0; i < 8; ++i) o[i] = f2us(acc[i]);
    int4 pkt;
    pkt.x = (int)o[0] | ((int)o[1] << 16);
    pkt.y = (int)o[2] | ((int)o[3] << 16);
    pkt.z = (int)o[4] | ((int)o[5] << 16);
    pkt.w = (int)o[6] | ((int)o[7] << 16);
    *reinterpret_cast<int4*>((ushort_t*)out + (size_t)bq * 256 + h * 32 + sub * 8) = pkt;
}

// ---------------------------------------------------------------------------
// LayerNorm over 256, bf16 input. Block = 4 waves = 4 rows, wave-per-row,
// shuffle-only. OUT_BF16: bf16 out (LN1->x_b) else f32 out (LN2->d_out).
// ---------------------------------------------------------------------------
template<bool OUT_BF16>
__global__ __launch_bounds__(256) void ln_kernel(
    const ushort_t* __restrict__ yb, const float* __restrict__ g,
    const float* __restrict__ bta, void* __restrict__ outv, int M)
{
    const int wave = threadIdx.x >> 6, lane = threadIdx.x & 63;
    const int row = blockIdx.x * 4 + wave;
    if (row >= M) return;
    const int2 raw = *reinterpret_cast<const int2*>(&yb[(size_t)row * 256 + lane * 4]);
    float v0 = us2f((ushort_t)((unsigned)raw.x & 0xffffu));
    float v1 = us2f((ushort_t)((unsigned)raw.x >> 16));
    float v2 = us2f((ushort_t)((unsigned)raw.y & 0xffffu));
    float v3 = us2f((ushort_t)((unsigned)raw.y >> 16));
    float s  = v0 + v1 + v2 + v3;
    float ss = v0 * v0 + v1 * v1 + v2 * v2 + v3 * v3;
    #pragma unroll
    for (int o = 32; o > 0; o >>= 1) {
        s += __shfl_down(s, o);
        ss += __shfl_down(ss, o);
    }
    s = __shfl(s, 0);
    ss = __shfl(ss, 0);
    const float mean = s * (1.f / 256.f);
    const float var = ss * (1.f / 256.f) - mean * mean;
    const float rs = rsqrtf(var + 1e-5f);
    const float4 g4 = *reinterpret_cast<const float4*>(&g[lane * 4]);
    const float4 b4 = *reinterpret_cast<const float4*>(&bta[lane * 4]);
    float4 o4;
    o4.x = (v0 - mean) * rs * g4.x + b4.x;
    o4.y = (v1 - mean) * rs * g4.y + b4.y;
    o4.z = (v2 - mean) * rs * g4.z + b4.z;
    o4.w = (v3 - mean) * rs * g4.w + b4.w;
    if (OUT_BF16) {
        int2 pk;
        pk.x = (unsigned)f2us(o4.x) | ((unsigned)f2us(o4.y) << 16);
        pk.y = (unsigned)f2us(o4.z) | ((unsigned)f2us(o4.w) << 16);
        *reinterpret_cast<int2*>((ushort_t*)outv + (size_t)row * 256 + lane * 4) = pk;
    } else {
        *reinterpret_cast<float4*>((float*)outv + (size_t)row * 256 + lane * 4) = o4;
    }
}

// ---------------------------------------------------------------------------
extern "C" void kernel_launch(void* const* d_in, const int* in_sizes, int n_in,
                              void* d_out, int out_size, void* d_ws, size_t ws_size,
                              hipStream_t stream)
{
    const int B = 2, L = 13343, C = 256, FF = 2048;
    const int M = B * L;  // 26686

    const float* src  = (const float*)d_in[0];
    const float* pos  = (const float*)d_in[1];
    const float* refp = (const float*)d_in[2];
    const float* wv   = (const float*)d_in[3];
    const float* bv   = (const float*)d_in[4];
    const float* wo   = (const float*)d_in[5];
    const float* bo   = (const float*)d_in[6];
    const float* wa   = (const float*)d_in[7];
    const float* ba   = (const float*)d_in[8];
    const float* wout = (const float*)d_in[9];
    const float* bout = (const float*)d_in[10];
    const float* ln1g = (const float*)d_in[11];
    const float* ln1b = (const float*)d_in[12];
    const float* w1   = (const float*)d_in[13];
    const float* b1   = (const float*)d_in[14];
    const float* w2   = (const float*)d_in[15];
    const float* b2   = (const float*)d_in[16];
    const float* ln2g = (const float*)d_in[17];
    const float* ln2b = (const float*)d_in[18];

    char* ws = (char*)d_ws;
    const size_t MB = 1ull << 20;
    // ---- workspace overlay (peak ~184 MB) ----
    bf16*  src_b  = (bf16*)(ws + 0);         // 13.7 MB
    bf16*  q_b    = (bf16*)(ws + 14 * MB);   // 13.7
    bf16*  val_b  = (bf16*)(ws + 28 * MB);   // 13.7
    bf16*  og     = (bf16*)(ws + 42 * MB);   // M*480 bf16 = 25.6 -> ends 67.6
    bf16*  acc_b  = (bf16*)(ws + 95 * MB);   // 13.7 -> ends 108.7
    bf16*  h_b    = (bf16*)(ws + 0);         // M*2048 bf16 = 109.3 (overlays dead)
    bf16*  y      = (bf16*)(ws + 110 * MB);  // 13.7 bf16 (dead after LN1)
    bf16*  z      = (bf16*)(ws + 110 * MB);  // overlays y (bf16)
    bf16*  x_b    = (bf16*)(ws + 138 * MB);  // 13.7 (resid + FFN1 input)
    bf16* wvt    = (bf16*)(ws + 152 * MB);   // 256*256
    bf16* wcat   = wvt + 256 * 256;          // 480*256
    bf16* woutt  = wcat + 480 * 256;         // 256*256
    bf16* w1t    = woutt + 256 * 256;        // 2048*256
    bf16* w2t    = w1t + 2048 * 256;         // 256*2048
    float* bcat  = (float*)(w2t + 256 * 2048); // 480 f32, ends ~154.6 MB
    (void)ws_size; (void)n_in; (void)in_sizes; (void)out_size;

    const int mt    = (M + 127) / 128;  // 209
    const int mt64  = (M + 63) / 64;    // 417
    const int sgrid = ((mt64 + 7) / 8) * 16;  // 848 blocks (pair-swizzled 1-D)
    const int lnb   = (M + 3) / 4;      // 6672

    // ---- fused weight prep (one launch) ----
    prep_kernel<<<1274, 256, 0, stream>>>(wv, wo, wa, wout, w1, w2, bo, ba,
                                          wvt, wcat, woutt, w1t, w2t, bcat);

    // ---- fused activation casts (float4) ----
    cast2_kernel<<<(M * C / 4 + 255) / 256, 256, 0, stream>>>(
        src, pos, src_b, q_b, M * C);

    // value = src @ wv + bv  (bf16)
    gemm_mfma_s<false, true, false, false><<<sgrid, 256, 0, stream>>>(
        (const ushort_t*)src_b, (const ushort_t*)wvt, bv, nullptr, val_b,
        M, 256, 256, mt64);

    // og = q @ [wo|wa] + [bo|ba]  (bf16, N=480)
    gemm_mfma<false, true, false><<<dim3(4, mt), 256, 0, stream>>>(
        (const ushort_t*)q_b, (const ushort_t*)wcat, bcat, nullptr, og, M, 480, 256);

    // deformable attention -> acc_b (bf16)
    msda_kernel_v3<<<(M + 7) / 8, 256, 0, stream>>>(
        (const ushort_t*)og, refp, (const ushort_t*)val_b, acc_b, M, L);

    // y = acc @ wout + bout + src  (bf16 out, f32 resid)
    gemm_mfma_s<false, true, true, false><<<sgrid, 256, 0, stream>>>(
        (const ushort_t*)acc_b, (const ushort_t*)woutt, bout, src, y,
        M, 256, 256, mt64);

    // x_b = LN1(y)  (bf16 in, bf16 out)
    ln_kernel<true><<<lnb, 256, 0, stream>>>(
        (const ushort_t*)y, ln1g, ln1b, x_b, M);

    // h = relu(x @ w1 + b1)  (bf16)
    gemm_mfma<true, true, false><<<dim3(16, mt), 256, 0, stream>>>(
        (const ushort_t*)x_b, (const ushort_t*)w1t, b1, nullptr, h_b, M, FF, 256);

    // z = h @ w2 + b2 + x  (bf16 out, bf16 resid = x_b)
    gemm_mfma_s<false, true, true, true><<<sgrid, 256, 0, stream>>>(
        (const ushort_t*)h_b, (const ushort_t*)w2t, b2, x_b, z,
        M, 256, FF, mt64);

    // out = LN2(z)  (bf16 in, f32 out)
    ln_kernel<false><<<lnb, 256, 0, stream>>>(
        (const ushort_t*)z, ln2g, ln2b, (float*)d_out, M);
}

// Round 14
// 391.626 us; speedup vs baseline: 2.5132x; 1.0188x over previous
//
#include <hip/hip_runtime.h>
#include <hip/hip_bf16.h>

typedef __hip_bfloat16 bf16;
typedef unsigned short ushort_t;
typedef __attribute__((ext_vector_type(8))) short bf16x8;
typedef __attribute__((ext_vector_type(16))) float f32x16;

__device__ __forceinline__ float us2f(unsigned short u) {
    unsigned int x = ((unsigned int)u) << 16;
    return __uint_as_float(x);
}
__device__ __forceinline__ ushort_t f2us(float f) {
    return ((__hip_bfloat16_raw)__float2bfloat16(f)).x;
}

// async global->LDS, 16 B per lane. LDS dest = wave-uniform base + lane*16.
__device__ __forceinline__ void gl_lds16(const ushort_t* g, ushort_t* l) {
    __builtin_amdgcn_global_load_lds(
        (const __attribute__((address_space(1))) void*)g,
        (__attribute__((address_space(3))) void*)l, 16, 0, 0);
}

// ---------------------------------------------------------------------------
// Fused input cast (float4): src_b = bf16(src), q_b = bf16(src + pos)
// ---------------------------------------------------------------------------
__global__ __launch_bounds__(256) void cast2_kernel(
    const float* __restrict__ src, const float* __restrict__ pos,
    bf16* __restrict__ src_b, bf16* __restrict__ q_b, int n)
{
    int i = (blockIdx.x * 256 + threadIdx.x) * 4;
    if (i < n) {
        const float4 s4 = *reinterpret_cast<const float4*>(&src[i]);
        const float4 p4 = *reinterpret_cast<const float4*>(&pos[i]);
        int2 sp, qp;
        sp.x = (unsigned)f2us(s4.x) | ((unsigned)f2us(s4.y) << 16);
        sp.y = (unsigned)f2us(s4.z) | ((unsigned)f2us(s4.w) << 16);
        qp.x = (unsigned)f2us(s4.x + p4.x) | ((unsigned)f2us(s4.y + p4.y) << 16);
        qp.y = (unsigned)f2us(s4.z + p4.z) | ((unsigned)f2us(s4.w + p4.w) << 16);
        *reinterpret_cast<int2*>((ushort_t*)src_b + i) = sp;
        *reinterpret_cast<int2*>((ushort_t*)q_b + i) = qp;
    }
}

// ---------------------------------------------------------------------------
// Fused weight prep: all transpose-casts + bias concat in ONE launch.
// ---------------------------------------------------------------------------
__global__ __launch_bounds__(256) void prep_kernel(
    const float* __restrict__ wv, const float* __restrict__ wo,
    const float* __restrict__ wa, const float* __restrict__ wout,
    const float* __restrict__ w1, const float* __restrict__ w2,
    const float* __restrict__ bo, const float* __restrict__ ba,
    bf16* __restrict__ wvt, bf16* __restrict__ wcat, bf16* __restrict__ woutt,
    bf16* __restrict__ w1t, bf16* __restrict__ w2t, float* __restrict__ bcat)
{
    __shared__ float tile[32][33];
    const int b = blockIdx.x;
    const float* W; bf16* Wt; int K, N, tb;
    if (b < 64)        { W = wv;   Wt = wvt;            K = 256;  N = 256;  tb = b; }
    else if (b < 144)  { W = wo;   Wt = wcat;           K = 256;  N = 320;  tb = b - 64; }
    else if (b < 184)  { W = wa;   Wt = wcat + 320*256; K = 256;  N = 160;  tb = b - 144; }
    else if (b < 248)  { W = wout; Wt = woutt;          K = 256;  N = 256;  tb = b - 184; }
    else if (b < 760)  { W = w1;   Wt = w1t;            K = 256;  N = 2048; tb = b - 248; }
    else if (b < 1272) { W = w2;   Wt = w2t;            K = 2048; N = 256;  tb = b - 760; }
    else {
        int i = (b - 1272) * 256 + threadIdx.x;
        if (i < 320) bcat[i] = bo[i];
        else if (i < 480) bcat[i] = ba[i - 320];
        return;
    }
    const int ntn = N >> 5;
    const int nb = (tb % ntn) * 32, kb = (tb / ntn) * 32;
    const int tx = threadIdx.x & 31, ty = threadIdx.x >> 5;  // 32 x 8
    #pragma unroll
    for (int i = 0; i < 32; i += 8) {
        int k = kb + ty + i, n = nb + tx;
        tile[ty + i][tx] = (k < K && n < N) ? W[(size_t)k * N + n] : 0.f;
    }
    __syncthreads();
    #pragma unroll
    for (int i = 0; i < 32; i += 8) {
        int n = nb + ty + i, k = kb + tx;
        if (n < N && k < K)
            Wt[(size_t)n * K + k] = __float2bfloat16(tile[tx][ty + i]);
    }
}

// ---------------------------------------------------------------------------
// MFMA bf16 GEMM (64x128 tile, M-split). R9-proven core + scalar epilogue.
// NT = n-tiles (pow2), pair-swizzled 1-D grid: the NT n-tiles of one m-tile
// sit 8 blocks apart => same XCD under %8 round-robin => A-rows L2-hit.
// WPE = waves/EU for __launch_bounds__: 8 for low-pressure instantiations
// (28 VGPR + 32 AGPR = 60 <= 64 regs -> 8 blocks/CU), 4 for proven users.
// ---------------------------------------------------------------------------
template<bool RELU, bool OUT_BF16, bool HAS_RESID, bool RESID_BF16, int NT, int WPE>
__global__ __launch_bounds__(256, WPE) void gemm_mfma_s(
    const ushort_t* __restrict__ A,    // [M][K] bf16
    const ushort_t* __restrict__ Bt,   // [N][K] bf16
    const float* __restrict__ bias,    // [N] f32
    const void* __restrict__ residv,   // [M][N] f32 or bf16
    void* __restrict__ outv, int M, int N, int K, int mtiles)
{
    __shared__ ushort_t Asmem[64 * 32];
    __shared__ ushort_t Bsmem[128 * 32];
    const int lid = blockIdx.x;
    const int tbk = lid >> 3;
    const int xb = tbk & (NT - 1);
    const int yg = (tbk / NT) * 8 + (lid & 7);
    if (yg >= mtiles) return;
    const int m0 = yg * 64;
    const int n0 = xb * 128;

    const int tid = threadIdx.x;
    const int lane = tid & 63;
    const int wave = tid >> 6;
    const int l32 = lane & 31;
    const int hi  = lane >> 5;
    const int wm = wave >> 1;
    const int wn = wave & 1;

    const int srow = lane >> 2;
    const int sch  = (lane & 3) * 8;

    int mA = m0 + wave * 16 + srow; if (mA > M - 1) mA = M - 1;
    const ushort_t* aP = A + (size_t)mA * K + sch;
    ushort_t* aL = &Asmem[(wave * 16) * 32];
    const ushort_t* bP[2]; ushort_t* bL[2];
    #pragma unroll
    for (int i = 0; i < 2; ++i) {
        const int rbase = wave * 32 + i * 16;
        int nB = n0 + rbase + srow; if (nB > N - 1) nB = N - 1;
        bP[i] = Bt + (size_t)nB * K + sch;
        bL[i] = &Bsmem[rbase * 32];
    }

    f32x16 acc[2] = {};

    for (int k0 = 0; k0 < K; k0 += 32) {
        gl_lds16(aP, aL);       aP    += 32;
        gl_lds16(bP[0], bL[0]); bP[0] += 32;
        gl_lds16(bP[1], bL[1]); bP[1] += 32;
        __syncthreads();

        #pragma unroll
        for (int kw = 0; kw < 2; ++kw) {
            const bf16x8 af = *reinterpret_cast<const bf16x8*>(
                &Asmem[(wm * 32 + l32) * 32 + kw * 16 + hi * 8]);
            bf16x8 bfr[2];
            #pragma unroll
            for (int j = 0; j < 2; ++j) {
                const int rowB = wn * 64 + j * 32 + l32;
                bfr[j] = *reinterpret_cast<const bf16x8*>(
                    &Bsmem[rowB * 32 + kw * 16 + hi * 8]);
            }
            #pragma unroll
            for (int j = 0; j < 2; ++j)
                acc[j] = __builtin_amdgcn_mfma_f32_32x32x16_bf16(
                    af, bfr[j], acc[j], 0, 0, 0);
        }
        __syncthreads();
    }

    const int mb = m0 + wm * 32 + hi * 4;
    #pragma unroll
    for (int j = 0; j < 2; ++j) {
        const int n = n0 + wn * 64 + j * 32 + l32;
        if (n >= N) continue;
        const float bval = bias[n];
        #pragma unroll
        for (int r = 0; r < 16; ++r) {
            const int m = mb + (r & 3) + (r >> 2) * 8;
            if (m >= M) continue;
            float v = acc[j][r] + bval;
            if (HAS_RESID) {
                if (RESID_BF16)
                    v += us2f(((const ushort_t*)residv)[(size_t)m * N + n]);
                else
                    v += ((const float*)residv)[(size_t)m * N + n];
            }
            if (RELU) v = fmaxf(v, 0.f);
            if (OUT_BF16)
                ((bf16*)outv)[(size_t)m * N + n] = __float2bfloat16(v);
            else
                ((float*)outv)[(size_t)m * N + n] = v;
        }
    }
}

// ---------------------------------------------------------------------------
// MS-deformable attention v3 (og bf16).
// ---------------------------------------------------------------------------
__global__ __launch_bounds__(256) void msda_kernel_v3(
    const ushort_t* __restrict__ og,     // [M,480] bf16: offs 0..319, logits 320..479
    const float* __restrict__ refp,      // [M,10]
    const ushort_t* __restrict__ value,  // [M,256] bf16 = (B,L,H,32)
    bf16* __restrict__ out,              // [M,256] bf16
    int M, int L)
{
    const int tid = threadIdx.x;
    const int qbase = blockIdx.x * 8;

    __shared__ float  s_attn[8][160];
    __shared__ int2   s_off[1280];
    __shared__ float4 s_w[1280];
    __shared__ int    s_Wl[5], s_St[5];

    if (tid < 5) {
        const int HW[5] = {100, 50, 25, 13, 7};
        const int st[5] = {0, 10000, 12500, 13125, 13294};
        s_Wl[tid] = HW[tid];
        s_St[tid] = st[tid];
    }

    for (int i = tid; i < 1280; i += 256) {
        int q = i / 160, j = i - q * 160;
        int qq = qbase + q;
        s_attn[q][j] = (qq < M) ? us2f(og[(size_t)qq * 480 + 320 + j]) : 0.f;
    }
    __syncthreads();

    if (tid < 64) {
        float* a = &s_attn[tid >> 3][(tid & 7) * 20];
        float mx = -1e30f;
        #pragma unroll
        for (int i = 0; i < 20; ++i) mx = fmaxf(mx, a[i]);
        float ssum = 0.f;
        #pragma unroll
        for (int i = 0; i < 20; ++i) {
            float e = __expf(a[i] - mx);
            a[i] = e;
            ssum += e;
        }
        float inv = 1.f / ssum;
        #pragma unroll
        for (int i = 0; i < 20; ++i) a[i] *= inv;
    }
    __syncthreads();

    #pragma unroll
    for (int it = 0; it < 5; ++it) {
        const int t = tid + it * 256;
        const int q  = t / 160;
        const int r  = t - q * 160;
        const int l  = (r - (r / 20) * 20) >> 2;
        const int qq = qbase + q;

        int2 offp = {0, 0};
        float4 wp = {0.f, 0.f, 0.f, 0.f};
        if (qq < M) {
            const int Wi = s_Wl[l];
            const int s0 = s_St[l];
            const float Wf = (float)Wi;
            const float ox = us2f(og[(size_t)qq * 480 + r * 2]);
            const float oy = us2f(og[(size_t)qq * 480 + r * 2 + 1]);
            const float2 rf = *reinterpret_cast<const float2*>(
                &refp[(size_t)qq * 10 + l * 2]);
            const float a = s_attn[q][r];

            const float px = fmaf(rf.x, Wf, -0.5f) + ox;
            const float py = fmaf(rf.y, Wf, -0.5f) + oy;
            const float x0f = floorf(px);
            const float y0f = floorf(py);
            const float lx = px - x0f;
            const float ly = py - y0f;
            const int x0 = (int)x0f;
            const int y0 = (int)y0f;

            const float wx0v = (x0 >= 0 && x0 < Wi) ? (1.f - lx) : 0.f;
            const float wx1v = (x0 + 1 >= 0 && x0 + 1 < Wi) ? lx : 0.f;
            const float wy0v = (y0 >= 0 && y0 < Wi) ? (1.f - ly) : 0.f;
            const float wy1v = (y0 + 1 >= 0 && y0 + 1 < Wi) ? ly : 0.f;

            const int c0 = min(max(x0, 0), Wi - 2);
            const int r0 = min(max(y0, 0), Wi - 2);
            const float swx0 = (x0 == c0 ? wx0v : 0.f) + (x0 + 1 == c0 ? wx1v : 0.f);
            const float swx1 = (x0 == c0 + 1 ? wx0v : 0.f) + (x0 + 1 == c0 + 1 ? wx1v : 0.f);
            const float swy0 = (y0 == r0 ? wy0v : 0.f) + (y0 + 1 == r0 ? wy1v : 0.f);
            const float swy1 = (y0 == r0 + 1 ? wy0v : 0.f) + (y0 + 1 == r0 + 1 ? wy1v : 0.f);

            offp.x = (s0 + r0 * Wi + c0) * 512;
            offp.y = offp.x + Wi * 512;
            wp.x = a * swx0 * swy0;
            wp.y = a * swx1 * swy0;
            wp.z = a * swx0 * swy1;
            wp.w = a * swx1 * swy1;
        }
        s_off[t] = offp;
        s_w[t] = wp;
    }
    __syncthreads();

    const int qi  = tid >> 5;
    const int g   = tid & 31;
    const int h   = g >> 2;
    const int sub = g & 3;
    const int bq = qbase + qi;
    if (bq >= M) return;
    const int b = bq / L;

    const char* vb = (const char*)value + (size_t)b * L * 512 + h * 64 + sub * 16;

    float acc[8] = {};
    const int tb = qi * 160 + h * 20;
    #pragma unroll 2
    for (int p = 0; p < 20; ++p) {
        const int2 off = s_off[tb + p];
        const float4 w = s_w[tb + p];
        const int4 u00 = *reinterpret_cast<const int4*>(vb + off.x);
        const int4 u10 = *reinterpret_cast<const int4*>(vb + off.x + 512);
        const int4 u01 = *reinterpret_cast<const int4*>(vb + off.y);
        const int4 u11 = *reinterpret_cast<const int4*>(vb + off.y + 512);
        #define ACC4(u, wt)                                                        \
            acc[0] = fmaf(wt, __uint_as_float((unsigned)(u).x << 16), acc[0]);      \
            acc[1] = fmaf(wt, __uint_as_float((unsigned)(u).x & 0xffff0000u), acc[1]); \
            acc[2] = fmaf(wt, __uint_as_float((unsigned)(u).y << 16), acc[2]);      \
            acc[3] = fmaf(wt, __uint_as_float((unsigned)(u).y & 0xffff0000u), acc[3]); \
            acc[4] = fmaf(wt, __uint_as_float((unsigned)(u).z << 16), acc[4]);      \
            acc[5] = fmaf(wt, __uint_as_float((unsigned)(u).z & 0xffff0000u), acc[5]); \
            acc[6] = fmaf(wt, __uint_as_float((unsigned)(u).w << 16), acc[6]);      \
            acc[7] = fmaf(wt, __uint_as_float((unsigned)(u).w & 0xffff0000u), acc[7]);
        ACC4(u00, w.x)
        ACC4(u10, w.y)
        ACC4(u01, w.z)
        ACC4(u11, w.w)
        #undef ACC4
    }

    ushort_t o[8];
    #pragma unroll
    for (int i = 0; i < 8; ++i) o[i] = f2us(acc[i]);
    int4 pkt;
    pkt.x = (int)o[0] | ((int)o[1] << 16);
    pkt.y = (int)o[2] | ((int)o[3] << 16);
    pkt.z = (int)o[4] | ((int)o[5] << 16);
    pkt.w = (int)o[6] | ((int)o[7] << 16);
    *reinterpret_cast<int4*>((ushort_t*)out + (size_t)bq * 256 + h * 32 + sub * 8) = pkt;
}

// ---------------------------------------------------------------------------
// LayerNorm over 256, bf16 input. Block = 4 waves = 4 rows, wave-per-row,
// shuffle-only. OUT_BF16: bf16 out (LN1->x_b) else f32 out (LN2->d_out).
// ---------------------------------------------------------------------------
template<bool OUT_BF16>
__global__ __launch_bounds__(256) void ln_kernel(
    const ushort_t* __restrict__ yb, const float* __restrict__ g,
    const float* __restrict__ bta, void* __restrict__ outv, int M)
{
    const int wave = threadIdx.x >> 6, lane = threadIdx.x & 63;
    const int row = blockIdx.x * 4 + wave;
    if (row >= M) return;
    const int2 raw = *reinterpret_cast<const int2*>(&yb[(size_t)row * 256 + lane * 4]);
    float v0 = us2f((ushort_t)((unsigned)raw.x & 0xffffu));
    float v1 = us2f((ushort_t)((unsigned)raw.x >> 16));
    float v2 = us2f((ushort_t)((unsigned)raw.y & 0xffffu));
    float v3 = us2f((ushort_t)((unsigned)raw.y >> 16));
    float s  = v0 + v1 + v2 + v3;
    float ss = v0 * v0 + v1 * v1 + v2 * v2 + v3 * v3;
    #pragma unroll
    for (int o = 32; o > 0; o >>= 1) {
        s += __shfl_down(s, o);
        ss += __shfl_down(ss, o);
    }
    s = __shfl(s, 0);
    ss = __shfl(ss, 0);
    const float mean = s * (1.f / 256.f);
    const float var = ss * (1.f / 256.f) - mean * mean;
    const float rs = rsqrtf(var + 1e-5f);
    const float4 g4 = *reinterpret_cast<const float4*>(&g[lane * 4]);
    const float4 b4 = *reinterpret_cast<const float4*>(&bta[lane * 4]);
    float4 o4;
    o4.x = (v0 - mean) * rs * g4.x + b4.x;
    o4.y = (v1 - mean) * rs * g4.y + b4.y;
    o4.z = (v2 - mean) * rs * g4.z + b4.z;
    o4.w = (v3 - mean) * rs * g4.w + b4.w;
    if (OUT_BF16) {
        int2 pk;
        pk.x = (unsigned)f2us(o4.x) | ((unsigned)f2us(o4.y) << 16);
        pk.y = (unsigned)f2us(o4.z) | ((unsigned)f2us(o4.w) << 16);
        *reinterpret_cast<int2*>((ushort_t*)outv + (size_t)row * 256 + lane * 4) = pk;
    } else {
        *reinterpret_cast<float4*>((float*)outv + (size_t)row * 256 + lane * 4) = o4;
    }
}

// ---------------------------------------------------------------------------
extern "C" void kernel_launch(void* const* d_in, const int* in_sizes, int n_in,
                              void* d_out, int out_size, void* d_ws, size_t ws_size,
                              hipStream_t stream)
{
    const int B = 2, L = 13343, C = 256, FF = 2048;
    const int M = B * L;  // 26686

    const float* src  = (const float*)d_in[0];
    const float* pos  = (const float*)d_in[1];
    const float* refp = (const float*)d_in[2];
    const float* wv   = (const float*)d_in[3];
    const float* bv   = (const float*)d_in[4];
    const float* wo   = (const float*)d_in[5];
    const float* bo   = (const float*)d_in[6];
    const float* wa   = (const float*)d_in[7];
    const float* ba   = (const float*)d_in[8];
    const float* wout = (const float*)d_in[9];
    const float* bout = (const float*)d_in[10];
    const float* ln1g = (const float*)d_in[11];
    const float* ln1b = (const float*)d_in[12];
    const float* w1   = (const float*)d_in[13];
    const float* b1   = (const float*)d_in[14];
    const float* w2   = (const float*)d_in[15];
    const float* b2   = (const float*)d_in[16];
    const float* ln2g = (const float*)d_in[17];
    const float* ln2b = (const float*)d_in[18];

    char* ws = (char*)d_ws;
    const size_t MB = 1ull << 20;
    // ---- workspace overlay (peak ~155 MB) ----
    bf16*  src_b  = (bf16*)(ws + 0);         // 13.7 MB
    bf16*  q_b    = (bf16*)(ws + 14 * MB);   // 13.7
    bf16*  val_b  = (bf16*)(ws + 28 * MB);   // 13.7
    bf16*  og     = (bf16*)(ws + 42 * MB);   // M*480 bf16 = 25.6 -> ends 67.6
    bf16*  acc_b  = (bf16*)(ws + 95 * MB);   // 13.7 -> ends 108.7
    bf16*  h_b    = (bf16*)(ws + 0);         // M*2048 bf16 = 109.3 (overlays dead)
    bf16*  y      = (bf16*)(ws + 110 * MB);  // 13.7 bf16 (dead after LN1)
    bf16*  z      = (bf16*)(ws + 110 * MB);  // overlays y (bf16)
    bf16*  x_b    = (bf16*)(ws + 138 * MB);  // 13.7 (resid + FFN1 input)
    bf16* wvt    = (bf16*)(ws + 152 * MB);   // 256*256
    bf16* wcat   = wvt + 256 * 256;          // 480*256
    bf16* woutt  = wcat + 480 * 256;         // 256*256
    bf16* w1t    = woutt + 256 * 256;        // 2048*256
    bf16* w2t    = w1t + 2048 * 256;         // 256*2048
    float* bcat  = (float*)(w2t + 256 * 2048); // 480 f32, ends ~154.6 MB
    (void)ws_size; (void)n_in; (void)in_sizes; (void)out_size;

    const int mt64 = (M + 63) / 64;        // 417
    const int gm8  = (mt64 + 7) / 8;       // 53
    const int lnb  = (M + 3) / 4;          // 6672

    // ---- fused weight prep (one launch) ----
    prep_kernel<<<1274, 256, 0, stream>>>(wv, wo, wa, wout, w1, w2, bo, ba,
                                          wvt, wcat, woutt, w1t, w2t, bcat);

    // ---- fused activation casts (float4) ----
    cast2_kernel<<<(M * C / 4 + 255) / 256, 256, 0, stream>>>(
        src, pos, src_b, q_b, M * C);

    // value = src @ wv + bv  (bf16)  [NT=2, WPE=4 — proven]
    gemm_mfma_s<false, true, false, false, 2, 4><<<gm8 * 16, 256, 0, stream>>>(
        (const ushort_t*)src_b, (const ushort_t*)wvt, bv, nullptr, val_b,
        M, 256, 256, mt64);

    // og = q @ [wo|wa] + [bo|ba]  (bf16, N=480)  [NT=4, WPE=8]
    gemm_mfma_s<false, true, false, false, 4, 8><<<gm8 * 32, 256, 0, stream>>>(
        (const ushort_t*)q_b, (const ushort_t*)wcat, bcat, nullptr, og,
        M, 480, 256, mt64);

    // deformable attention -> acc_b (bf16)
    msda_kernel_v3<<<(M + 7) / 8, 256, 0, stream>>>(
        (const ushort_t*)og, refp, (const ushort_t*)val_b, acc_b, M, L);

    // y = acc @ wout + bout + src  (bf16 out, f32 resid)  [NT=2, WPE=4]
    gemm_mfma_s<false, true, true, false, 2, 4><<<gm8 * 16, 256, 0, stream>>>(
        (const ushort_t*)acc_b, (const ushort_t*)woutt, bout, src, y,
        M, 256, 256, mt64);

    // x_b = LN1(y)  (bf16 in, bf16 out)
    ln_kernel<true><<<lnb, 256, 0, stream>>>(
        (const ushort_t*)y, ln1g, ln1b, x_b, M);

    // h = relu(x @ w1 + b1)  (bf16, N=2048)  [NT=16, WPE=8 — occupancy 2x]
    gemm_mfma_s<true, true, false, false, 16, 8><<<gm8 * 128, 256, 0, stream>>>(
        (const ushort_t*)x_b, (const ushort_t*)w1t, b1, nullptr, h_b,
        M, FF, 256, mt64);

    // z = h @ w2 + b2 + x  (bf16 out, bf16 resid = x_b)  [NT=2, WPE=4]
    gemm_mfma_s<false, true, true, true, 2, 4><<<gm8 * 16, 256, 0, stream>>>(
        (const ushort_t*)h_b, (const ushort_t*)w2t, b2, x_b, z,
        M, 256, FF, mt64);

    // out = LN2(z)  (bf16 in, f32 out)
    ln_kernel<false><<<lnb, 256, 0, stream>>>(
        (const ushort_t*)z, ln2g, ln2b, (float*)d_out, M);
}